// Round 3
// baseline (2006.776 us; speedup 1.0000x reference)
//
#include <hip/hip_runtime.h>
#include <math.h>

// Problem constants: T=2048, B=256, H=128, IN_DIM=1, NUM_DATA=4096
#define T_STEPS 2048
#define BATCH   256
#define HDIM    128

__device__ __forceinline__ float fast_rcp(float x) { return __builtin_amdgcn_rcpf(x); }
__device__ __forceinline__ float sigmoid_f(float x) { return fast_rcp(1.0f + __expf(-x)); }
__device__ __forceinline__ float tanh_f(float x) {
    float e = __expf(2.0f * x);
    return 1.0f - 2.0f * fast_rcp(e + 1.0f);
}

#define REP8(M) M(0) M(1) M(2) M(3) M(4) M(5) M(6) M(7)

// R23 = R22 (gate-XOR tail, 1126us) + TWO BATCHES PER BLOCK (grid 128).
// The step skeleton (ds latency + activation chain + barrier) dominated:
// period 1429cy vs 819cy issue. Weights/seeds/scales are batch-invariant,
// so one block now runs two independent recurrences off the SAME 128
// weight VGPRs: batch B's ds_reads issue after GEMV A's last pk_fma
// (shared h buffer, WAR-safe), GEMV B's pk_fmas replace the s_nop hazard
// fillers of tail A, and tail B is the only exposed chain. Rings shrink
// to 64 slots x 144 words each (ring B at byte 36864 = 576*64, so the
// flush address formula histB+576*m+144*q covers BOTH rings via the
// m-split: lanes m<64 flush ring A slots, m>=64 ring B). W_lin left in
// global (re-fetched each flush, 1/64 iters) to fit VGPRs: clobber v0-219
// + 26 inputs = 246 <= 256 -> 2 waves/SIMD kept. Batch-A op sequence is
// bit-identical to R22.
// Register map: h v[0:31] (shared A/B), weights v[32:159],
// accA v[160:167], accB v[168:175], cA v176, cB v177, hnA v178, hnB v179,
// tmp v180-183, rdA v184, rdB v185, wrA v186, wrB v187, vD v188,
// fR v189, jO v191, outaddr v192, seeds v[196:203], flush-wl v[160:175]
// + v[204:219] (acc regs are dead during flush).
__global__ __launch_bounds__(512, 2)
void lstm_seq_kernel(const int*   __restrict__ label,
                     const float* __restrict__ h0,     // (1, 4096, 128)
                     const float* __restrict__ W_ih,   // (512, 1)
                     const float* __restrict__ W_hh,   // (512, 128)
                     const float* __restrict__ b_ih,   // (512,)
                     const float* __restrict__ b_hh,   // (512,)
                     const float* __restrict__ W_lin,  // (1, 128)
                     const float* __restrict__ b_lin,  // (1,)
                     float*       __restrict__ out)    // (T, B, 1)
{
    const int tid = threadIdx.x;
    const int blk = blockIdx.x;
    const int m   = tid >> 2;     // h element 0..127
    const int q   = tid & 3;      // K-quarter 0..3
    const int q8  = q * 8;

    const int ri = m, rf = m + 128, rg = m + 256, ro = m + 384;

    // Two rings of 64 slots x 144 words (pad 4 words / 32). Ring A words
    // 0..9215, ring B words 9216..18431. Slot k holds h_state_{k+1} of the
    // current 64-step window. Slot 63 of each ring doubles as h_init
    // scratch for the C prologue (overwritten at t=63).
    __shared__ __attribute__((aligned(16))) float hist[2 * 64 * 144];

    const float4* W4 = (const float4*)W_hh;
    const float4* L4 = (const float4*)W_lin;

    // ---- C-side load + fold (used only for step 0, for BOTH batches) ----
    #define DECL_W(i) \
        float4 wi##i = W4[ri * 32 + q8 + (i)]; \
        float4 wf##i = W4[rf * 32 + q8 + (i)]; \
        float4 wg##i = W4[rg * 32 + q8 + (i)]; \
        float4 wo##i = W4[ro * 32 + q8 + (i)];
    REP8(DECL_W)

    const float wih_i = W_ih[ri], wih_f = W_ih[rf];
    const float wih_g = W_ih[rg], wih_o = W_ih[ro];
    const float blin  = b_lin[0];

    const float bi_ = b_ih[ri] + b_hh[ri] + wih_i * blin;
    const float bf_ = b_ih[rf] + b_hh[rf] + wih_f * blin;
    const float bg_ = b_ih[rg] + b_hh[rg] + wih_g * blin;
    const float bo_ = b_ih[ro] + b_hh[ro] + wih_o * blin;

    // scaled quarter-seed biases: s_gate * bias / 4 (bit-identical consts)
    const float SNEG = -0x1.715476p+0f;   // -log2e = 0xBFB8AA3B
    const float SG   =  0x1.715476p+1f;   // 2log2e = 0x4038AA3B
    const float sI  = bi_ * 0.25f * SNEG;
    const float sF  = bf_ * 0.25f * SNEG;
    const float sG_ = bg_ * 0.25f * SG;
    const float sO  = bo_ * 0.25f * SNEG;

    // ---- gate-XOR permutation (slot p on lane q holds gate p^q) ----
    const float b0s = (q==0)?sI :(q==1)?sF :(q==2)?sG_:sO;
    const float b1s = (q==0)?sF :(q==1)?sI :(q==2)?sO :sG_;
    const float b2s = (q==0)?sG_:(q==1)?sO :(q==2)?sI :sF;
    const float b3s = (q==0)?sO :(q==1)?sG_:(q==2)?sF :sI;
    const float wihA = (q==0)?wih_i:(q==1)?wih_f:(q==2)?wih_g:wih_o;
    const float wihB = (q==0)?wih_f:(q==1)?wih_i:(q==2)?wih_o:wih_g;
    const float wihC = (q==0)?wih_g:(q==1)?wih_o:(q==2)?wih_i:wih_f;
    const float wihD = (q==0)?wih_o:(q==1)?wih_g:(q==2)?wih_f:wih_i;
    const float sc0 = ( q    == 2) ? SG : SNEG;
    const float sc1 = ((q^1) == 2) ? SG : SNEG;
    const float sc2 = ((q^2) == 2) ? SG : SNEG;
    const float sc3 = ((q^3) == 2) ? SG : SNEG;
    const float caq = (q==2) ? -2.0f : 1.0f;
    const float cbq = (q==2) ?  1.0f : 0.0f;

    #define FOLD_W(i) { float4 lv = L4[q8 + (i)]; \
        wi##i.x = fmaf(wih_i, lv.x, wi##i.x); wi##i.y = fmaf(wih_i, lv.y, wi##i.y); \
        wi##i.z = fmaf(wih_i, lv.z, wi##i.z); wi##i.w = fmaf(wih_i, lv.w, wi##i.w); \
        wf##i.x = fmaf(wih_f, lv.x, wf##i.x); wf##i.y = fmaf(wih_f, lv.y, wf##i.y); \
        wf##i.z = fmaf(wih_f, lv.z, wf##i.z); wf##i.w = fmaf(wih_f, lv.w, wf##i.w); \
        wg##i.x = fmaf(wih_g, lv.x, wg##i.x); wg##i.y = fmaf(wih_g, lv.y, wg##i.y); \
        wg##i.z = fmaf(wih_g, lv.z, wg##i.z); wg##i.w = fmaf(wih_g, lv.w, wg##i.w); \
        wo##i.x = fmaf(wih_o, lv.x, wo##i.x); wo##i.y = fmaf(wih_o, lv.y, wo##i.y); \
        wo##i.z = fmaf(wih_o, lv.z, wo##i.z); wo##i.w = fmaf(wih_o, lv.w, wo##i.w); }
    REP8(FOLD_W)

    const int   lane  = tid & 63;
    const int   ya0w  = lane + ((lane >> 5) << 2);
    const float wl_a  = W_lin[lane];
    const float wl_b  = W_lin[lane + 64];
    const int   hword = m + ((m >> 5) << 2);

    // ---- init h into slot 63 of each ring (scratch) ----
    float* slotI_A = &hist[144 * 63];
    float* slotI_B = &hist[144 * 127];
    if (tid < HDIM) {
        slotI_A[tid + ((tid >> 5) << 2)] = h0[label[2*blk  ] * HDIM + tid];
        slotI_B[tid + ((tid >> 5) << 2)] = h0[label[2*blk+1] * HDIM + tid];
    }
    __syncthreads();

    // y_init per batch for the t=0 bias correction
    float pA = slotI_A[ya0w] * wl_a + slotI_A[ya0w + 72] * wl_b;
    float pB = slotI_B[ya0w] * wl_a + slotI_B[ya0w + 72] * wl_b;
    #pragma unroll
    for (int off = 1; off < 64; off <<= 1) {
        pA += __shfl_xor(pA, off, 64);
        pB += __shfl_xor(pB, off, 64);
    }
    const float y0A = pA + blin;
    const float y0B = pB + blin;

    // ---- step 0 in C for both batches ----
    float cA, cB;
    {
        const float cbi = bi_ - wih_i * y0A;
        const float cbf = bf_ - wih_f * y0A;
        const float cbg = bg_ - wih_g * y0A;
        const float cbo = bo_ - wih_o * y0A;
        const float4* hq0 = (const float4*)(slotI_A + 36 * q);
        float ai = 0.f, af = 0.f, ag = 0.f, ao = 0.f;
        #define DOT4(i) { float4 hv = hq0[(i)]; \
            ai = fmaf(hv.x, wi##i.x, ai); ai = fmaf(hv.y, wi##i.y, ai); \
            ai = fmaf(hv.z, wi##i.z, ai); ai = fmaf(hv.w, wi##i.w, ai); \
            af = fmaf(hv.x, wf##i.x, af); af = fmaf(hv.y, wf##i.y, af); \
            af = fmaf(hv.z, wf##i.z, af); af = fmaf(hv.w, wf##i.w, af); \
            ag = fmaf(hv.x, wg##i.x, ag); ag = fmaf(hv.y, wg##i.y, ag); \
            ag = fmaf(hv.z, wg##i.z, ag); ag = fmaf(hv.w, wg##i.w, ag); \
            ao = fmaf(hv.x, wo##i.x, ao); ao = fmaf(hv.y, wo##i.y, ao); \
            ao = fmaf(hv.z, wo##i.z, ao); ao = fmaf(hv.w, wo##i.w, ao); }
        REP8(DOT4)
        ai += __shfl_xor(ai, 1, 64); af += __shfl_xor(af, 1, 64);
        ag += __shfl_xor(ag, 1, 64); ao += __shfl_xor(ao, 1, 64);
        ai += __shfl_xor(ai, 2, 64); af += __shfl_xor(af, 2, 64);
        ag += __shfl_xor(ag, 2, 64); ao += __shfl_xor(ao, 2, 64);
        const float iv = sigmoid_f(ai + cbi);
        const float fv = sigmoid_f(af + cbf);
        const float gv = tanh_f  (ag + cbg);
        const float ov = sigmoid_f(ao + cbo);
        cA = iv * gv;
        const float hn0 = ov * tanh_f(cA);
        if (q == 0) hist[hword] = hn0;            // ring A slot 0 = state 1
    }
    {
        const float cbi = bi_ - wih_i * y0B;
        const float cbf = bf_ - wih_f * y0B;
        const float cbg = bg_ - wih_g * y0B;
        const float cbo = bo_ - wih_o * y0B;
        const float4* hq0 = (const float4*)(slotI_B + 36 * q);
        float ai = 0.f, af = 0.f, ag = 0.f, ao = 0.f;
        REP8(DOT4)
        ai += __shfl_xor(ai, 1, 64); af += __shfl_xor(af, 1, 64);
        ag += __shfl_xor(ag, 1, 64); ao += __shfl_xor(ao, 1, 64);
        ai += __shfl_xor(ai, 2, 64); af += __shfl_xor(af, 2, 64);
        ag += __shfl_xor(ag, 2, 64); ao += __shfl_xor(ao, 2, 64);
        const float iv = sigmoid_f(ai + cbi);
        const float fv = sigmoid_f(af + cbf);
        const float gv = tanh_f  (ag + cbg);
        const float ov = sigmoid_f(ao + cbo);
        cB = iv * gv;
        const float hn0 = ov * tanh_f(cB);
        if (q == 0) hist[9216 + hword] = hn0;     // ring B slot 0 = state 1
    }
    __syncthreads();

    // ---- asm operand prep ----
    const unsigned histB = (unsigned)(unsigned long long)(&hist[0]);
    const unsigned vR0 = histB + 144u * (unsigned)q;          // ring A slot0
    const unsigned hW0 = histB + 4u * (unsigned)hword;        // write base (advances before write)
    const unsigned vD0 = (unsigned)(144 * q - 4 * hword);     // read(t) - write(t)
    const unsigned fR0 = histB + 576u * (unsigned)m + 144u * (unsigned)q; // flush: covers BOTH rings via m
    const unsigned jO0 = 1024u * (unsigned)(m & 63) + (((unsigned)m >> 6) << 2); // out byte: slot*1024 (+4 for B half)
    const unsigned oA0 = 8u * (unsigned)blk;                  // out[0] byte for batch pair
    const unsigned off0 = (unsigned)((m + 128 * (q    )) * 512 + q * 128);
    const unsigned off1 = (unsigned)((m + 128 * (q ^ 1)) * 512 + q * 128);
    const unsigned off2 = (unsigned)((m + 128 * (q ^ 2)) * 512 + q * 128);
    const unsigned off3 = (unsigned)((m + 128 * (q ^ 3)) * 512 + q * 128);
    const unsigned offL = (unsigned)(q * 128);

    // GEMV B group K (K=0..15): h pair v[2K:2K+1] x 4 weight slots.
    #define PKB(K) \
      " v_pk_fma_f32 v[168:169], v[" #K "*2:" #K "*2+1], v[32+" #K "*2:33+" #K "*2], v[168:169]\n\t" \
      " v_pk_fma_f32 v[170:171], v[" #K "*2:" #K "*2+1], v[64+" #K "*2:65+" #K "*2], v[170:171]\n\t" \
      " v_pk_fma_f32 v[172:173], v[" #K "*2:" #K "*2+1], v[96+" #K "*2:97+" #K "*2], v[172:173]\n\t" \
      " v_pk_fma_f32 v[174:175], v[" #K "*2:" #K "*2+1], v[128+" #K "*2:129+" #K "*2], v[174:175]\n\t"

    asm volatile(
        // ---------------- prologue ----------------
        "v_mov_b32 v196, %[b0]\n\t"
        "v_mov_b32 v197, 0\n\t"
        "v_mov_b32 v198, %[b1]\n\t"
        "v_mov_b32 v199, 0\n\t"
        "v_mov_b32 v200, %[b2]\n\t"
        "v_mov_b32 v201, 0\n\t"
        "v_mov_b32 v202, %[b3]\n\t"
        "v_mov_b32 v203, 0\n\t"
        "v_mov_b32 v176, %[c0A]\n\t"
        "v_mov_b32 v177, %[c0B]\n\t"
        "v_mov_b32 v184, %[vR]\n\t"
        "v_add_u32 v185, 0x9000, v184\n\t"        // ring B read base (+36864)
        "v_mov_b32 v186, %[hW]\n\t"
        "v_add_u32 v187, 0x9000, v186\n\t"        // ring B write base
        "v_mov_b32 v188, %[vD]\n\t"
        "v_mov_b32 v189, %[fR]\n\t"
        "v_mov_b32 v191, %[jO]\n\t"
        "s_mov_b32 s26, 0x11111111\n\t"           // q==0 lane mask
        "s_mov_b32 s27, 0x11111111\n\t"
        "s_mov_b32 s28, %[oA]\n\t"                // out base byte (batch pair)
        // weights: 8x dwordx4 per slot (gate-XOR-permuted rows)
        "global_load_dwordx4 v[32:35], %[off0], %[whh] offset:0\n\t"
        "global_load_dwordx4 v[36:39], %[off0], %[whh] offset:16\n\t"
        "global_load_dwordx4 v[40:43], %[off0], %[whh] offset:32\n\t"
        "global_load_dwordx4 v[44:47], %[off0], %[whh] offset:48\n\t"
        "global_load_dwordx4 v[48:51], %[off0], %[whh] offset:64\n\t"
        "global_load_dwordx4 v[52:55], %[off0], %[whh] offset:80\n\t"
        "global_load_dwordx4 v[56:59], %[off0], %[whh] offset:96\n\t"
        "global_load_dwordx4 v[60:63], %[off0], %[whh] offset:112\n\t"
        "global_load_dwordx4 v[64:67], %[off1], %[whh] offset:0\n\t"
        "global_load_dwordx4 v[68:71], %[off1], %[whh] offset:16\n\t"
        "global_load_dwordx4 v[72:75], %[off1], %[whh] offset:32\n\t"
        "global_load_dwordx4 v[76:79], %[off1], %[whh] offset:48\n\t"
        "global_load_dwordx4 v[80:83], %[off1], %[whh] offset:64\n\t"
        "global_load_dwordx4 v[84:87], %[off1], %[whh] offset:80\n\t"
        "global_load_dwordx4 v[88:91], %[off1], %[whh] offset:96\n\t"
        "global_load_dwordx4 v[92:95], %[off1], %[whh] offset:112\n\t"
        "global_load_dwordx4 v[96:99], %[off2], %[whh] offset:0\n\t"
        "global_load_dwordx4 v[100:103], %[off2], %[whh] offset:16\n\t"
        "global_load_dwordx4 v[104:107], %[off2], %[whh] offset:32\n\t"
        "global_load_dwordx4 v[108:111], %[off2], %[whh] offset:48\n\t"
        "global_load_dwordx4 v[112:115], %[off2], %[whh] offset:64\n\t"
        "global_load_dwordx4 v[116:119], %[off2], %[whh] offset:80\n\t"
        "global_load_dwordx4 v[120:123], %[off2], %[whh] offset:96\n\t"
        "global_load_dwordx4 v[124:127], %[off2], %[whh] offset:112\n\t"
        "global_load_dwordx4 v[128:131], %[off3], %[whh] offset:0\n\t"
        "global_load_dwordx4 v[132:135], %[off3], %[whh] offset:16\n\t"
        "global_load_dwordx4 v[136:139], %[off3], %[whh] offset:32\n\t"
        "global_load_dwordx4 v[140:143], %[off3], %[whh] offset:48\n\t"
        "global_load_dwordx4 v[144:147], %[off3], %[whh] offset:64\n\t"
        "global_load_dwordx4 v[148:151], %[off3], %[whh] offset:80\n\t"
        "global_load_dwordx4 v[152:155], %[off3], %[whh] offset:96\n\t"
        "global_load_dwordx4 v[156:159], %[off3], %[whh] offset:112\n\t"
        // W_lin quarter-slice -> v[0:31] (TEMP: consumed by the fold)
        "global_load_dwordx4 v[0:3],   %[offL], %[wlin] offset:0\n\t"
        "global_load_dwordx4 v[4:7],   %[offL], %[wlin] offset:16\n\t"
        "global_load_dwordx4 v[8:11],  %[offL], %[wlin] offset:32\n\t"
        "global_load_dwordx4 v[12:15], %[offL], %[wlin] offset:48\n\t"
        "global_load_dwordx4 v[16:19], %[offL], %[wlin] offset:64\n\t"
        "global_load_dwordx4 v[20:23], %[offL], %[wlin] offset:80\n\t"
        "global_load_dwordx4 v[24:27], %[offL], %[wlin] offset:96\n\t"
        "global_load_dwordx4 v[28:31], %[offL], %[wlin] offset:112\n\t"
        "s_waitcnt vmcnt(0)\n\t"
        // fold W' = W + wih*W_lin, then exp2 pre-scale
        ".set K_I, 0\n"
        ".rept 32\n"
        " v_fma_f32 v[32+K_I],  %[wA], v[0+K_I], v[32+K_I]\n"
        " v_fma_f32 v[64+K_I],  %[wB], v[0+K_I], v[64+K_I]\n"
        " v_fma_f32 v[96+K_I],  %[wC], v[0+K_I], v[96+K_I]\n"
        " v_fma_f32 v[128+K_I], %[wD], v[0+K_I], v[128+K_I]\n"
        " .set K_I, K_I+1\n"
        ".endr\n"
        ".set K_I, 0\n"
        ".rept 32\n"
        " v_mul_f32 v[32+K_I],  %[sc0], v[32+K_I]\n"
        " v_mul_f32 v[64+K_I],  %[sc1], v[64+K_I]\n"
        " v_mul_f32 v[96+K_I],  %[sc2], v[96+K_I]\n"
        " v_mul_f32 v[128+K_I], %[sc3], v[128+K_I]\n"
        " .set K_I, K_I+1\n"
        ".endr\n"
        "s_movk_i32 s24, 1\n\t"
        // ---------------- main loop: t = 1 .. 2047 ----------------
        "1:\n\t"
        // ---- reads A: 8x b128 from ring A slot t-1 ----
        "ds_read_b128 v[0:3],   v184\n\t"
        "ds_read_b128 v[4:7],   v184 offset:16\n\t"
        "ds_read_b128 v[8:11],  v184 offset:32\n\t"
        "ds_read_b128 v[12:15], v184 offset:48\n\t"
        "ds_read_b128 v[16:19], v184 offset:64\n\t"
        "ds_read_b128 v[20:23], v184 offset:80\n\t"
        "ds_read_b128 v[24:27], v184 offset:96\n\t"
        "ds_read_b128 v[28:31], v184 offset:112\n\t"
        // ---- GEMV A (staggered lgkmcnt, seeds v[196:203]) ----
        "s_waitcnt lgkmcnt(6)\n\t"
        "v_pk_fma_f32 v[160:161], v[0:1], v[32:33], v[196:197]\n\t"
        "v_pk_fma_f32 v[162:163], v[0:1], v[64:65], v[198:199]\n\t"
        "v_pk_fma_f32 v[164:165], v[0:1], v[96:97], v[200:201]\n\t"
        "v_pk_fma_f32 v[166:167], v[0:1], v[128:129], v[202:203]\n\t"
        ".set K_I, 2\n"
        ".rept 3\n"
        " v_pk_fma_f32 v[160:161], v[K_I:K_I+1], v[32+K_I:33+K_I], v[160:161]\n"
        " v_pk_fma_f32 v[162:163], v[K_I:K_I+1], v[64+K_I:65+K_I], v[162:163]\n"
        " v_pk_fma_f32 v[164:165], v[K_I:K_I+1], v[96+K_I:97+K_I], v[164:165]\n"
        " v_pk_fma_f32 v[166:167], v[K_I:K_I+1], v[128+K_I:129+K_I], v[166:167]\n"
        " .set K_I, K_I+2\n"
        ".endr\n"
        "s_waitcnt lgkmcnt(4)\n\t"
        ".rept 4\n"
        " v_pk_fma_f32 v[160:161], v[K_I:K_I+1], v[32+K_I:33+K_I], v[160:161]\n"
        " v_pk_fma_f32 v[162:163], v[K_I:K_I+1], v[64+K_I:65+K_I], v[162:163]\n"
        " v_pk_fma_f32 v[164:165], v[K_I:K_I+1], v[96+K_I:97+K_I], v[164:165]\n"
        " v_pk_fma_f32 v[166:167], v[K_I:K_I+1], v[128+K_I:129+K_I], v[166:167]\n"
        " .set K_I, K_I+2\n"
        ".endr\n"
        "s_waitcnt lgkmcnt(2)\n\t"
        ".rept 4\n"
        " v_pk_fma_f32 v[160:161], v[K_I:K_I+1], v[32+K_I:33+K_I], v[160:161]\n"
        " v_pk_fma_f32 v[162:163], v[K_I:K_I+1], v[64+K_I:65+K_I], v[162:163]\n"
        " v_pk_fma_f32 v[164:165], v[K_I:K_I+1], v[96+K_I:97+K_I], v[164:165]\n"
        " v_pk_fma_f32 v[166:167], v[K_I:K_I+1], v[128+K_I:129+K_I], v[166:167]\n"
        " .set K_I, K_I+2\n"
        ".endr\n"
        "s_waitcnt lgkmcnt(0)\n\t"
        ".rept 4\n"
        " v_pk_fma_f32 v[160:161], v[K_I:K_I+1], v[32+K_I:33+K_I], v[160:161]\n"
        " v_pk_fma_f32 v[162:163], v[K_I:K_I+1], v[64+K_I:65+K_I], v[162:163]\n"
        " v_pk_fma_f32 v[164:165], v[K_I:K_I+1], v[96+K_I:97+K_I], v[164:165]\n"
        " v_pk_fma_f32 v[166:167], v[K_I:K_I+1], v[128+K_I:129+K_I], v[166:167]\n"
        " .set K_I, K_I+2\n"
        ".endr\n"
        // ---- reads B into v[0:31] (WAR-safe: all GEMV A ops issued) ----
        "ds_read_b128 v[0:3],   v185\n\t"
        "ds_read_b128 v[4:7],   v185 offset:16\n\t"
        "ds_read_b128 v[8:11],  v185 offset:32\n\t"
        "ds_read_b128 v[12:15], v185 offset:48\n\t"
        "ds_read_b128 v[16:19], v185 offset:64\n\t"
        "ds_read_b128 v[20:23], v185 offset:80\n\t"
        "ds_read_b128 v[24:27], v185 offset:96\n\t"
        "ds_read_b128 v[28:31], v185 offset:112\n\t"
        // ---- tail A interleaved with GEMV B (pk ops fill hazard gaps) ----
        "v_add_f32 v160, v160, v161\n\t"
        "v_add_f32 v161, v162, v163\n\t"
        "v_add_f32 v164, v164, v165\n\t"
        "v_add_f32 v165, v166, v167\n\t"
        "v_add_f32_dpp v160, v161, v160 quad_perm:[1,0,3,2] row_mask:0xf bank_mask:0xf\n\t"
        "v_add_u32 v186, 0x240, v186\n\t"          // wrA += 576
        "v_add_f32_dpp v164, v165, v164 quad_perm:[1,0,3,2] row_mask:0xf bank_mask:0xf\n\t"
        "v_add_u32 v184, v186, v188\n\t"           // rdA = wrA + vD
        "v_add_u32 v187, 0x240, v187\n\t"          // wrB += 576
        "v_add_f32_dpp v160, v164, v160 quad_perm:[2,3,0,1] row_mask:0xf bank_mask:0xf\n\t"
        "v_add_u32 v185, v187, v188\n\t"           // rdB = wrB + vD
        "s_waitcnt lgkmcnt(6)\n\t"
        "v_pk_fma_f32 v[168:169], v[0:1], v[32:33], v[196:197]\n\t"
        "v_pk_fma_f32 v[170:171], v[0:1], v[64:65], v[198:199]\n\t"
        "v_pk_fma_f32 v[172:173], v[0:1], v[96:97], v[200:201]\n\t"
        "v_pk_fma_f32 v[174:175], v[0:1], v[128:129], v[202:203]\n\t"
        "v_exp_f32 v160, v160\n\t"
        PKB(1)
        PKB(2)
        "v_add_f32 v160, 1.0, v160\n\t"
        PKB(3)
        "s_waitcnt lgkmcnt(4)\n\t"
        "v_rcp_f32 v160, v160\n\t"
        PKB(4)
        "v_fma_f32 v180, %[ca], v160, %[cb]\n\t"   // a_A
        PKB(5)
        "v_mul_f32_dpp v181, v180, v180 quad_perm:[2,3,0,1] row_mask:0xf bank_mask:0xf\n\t"
        PKB(6)
        "v_mov_b32_dpp v182, v180 quad_perm:[1,0,3,2] row_mask:0xf bank_mask:0xf\n\t"
        "v_mov_b32_dpp v183, v180 quad_perm:[3,3,3,3] row_mask:0xf bank_mask:0xf\n\t"
        PKB(7)
        "s_waitcnt lgkmcnt(2)\n\t"
        "v_fma_f32 v176, v182, v176, v181\n\t"     // c_A = f*c + i*g
        PKB(8)
        "v_mul_f32 v180, 0x4038aa3b, v176\n\t"
        PKB(9)
        "v_exp_f32 v180, v180\n\t"
        PKB(10)
        "v_add_f32 v180, 1.0, v180\n\t"
        PKB(11)
        "s_waitcnt lgkmcnt(0)\n\t"
        "v_rcp_f32 v180, v180\n\t"
        PKB(12)
        "v_fma_f32 v180, -2.0, v180, 1.0\n\t"
        PKB(13)
        "v_mul_f32 v178, v183, v180\n\t"           // hn_A
        PKB(14)
        "s_mov_b64 s[22:23], exec\n\t"
        "s_mov_b64 exec, s[26:27]\n\t"
        "ds_write_b32 v186, v178\n\t"
        "s_mov_b64 exec, s[22:23]\n\t"
        PKB(15)
        // ---- tail B (exposed; R22 hazard spacing) ----
        "v_add_f32 v168, v168, v169\n\t"
        "v_add_f32 v169, v170, v171\n\t"
        "v_add_f32 v172, v172, v173\n\t"
        "v_add_f32 v173, v174, v175\n\t"
        "s_nop 1\n\t"
        "v_add_f32_dpp v168, v169, v168 quad_perm:[1,0,3,2] row_mask:0xf bank_mask:0xf\n\t"
        "v_add_f32_dpp v172, v173, v172 quad_perm:[1,0,3,2] row_mask:0xf bank_mask:0xf\n\t"
        "s_nop 1\n\t"
        "v_add_f32_dpp v168, v172, v168 quad_perm:[2,3,0,1] row_mask:0xf bank_mask:0xf\n\t"
        "s_nop 3\n\t"
        "v_exp_f32 v168, v168\n\t"
        "s_nop 1\n\t"
        "v_add_f32 v168, 1.0, v168\n\t"
        "v_rcp_f32 v168, v168\n\t"
        "s_nop 1\n\t"
        "v_fma_f32 v180, %[ca], v168, %[cb]\n\t"   // a_B
        "s_nop 3\n\t"
        "v_mul_f32_dpp v181, v180, v180 quad_perm:[2,3,0,1] row_mask:0xf bank_mask:0xf\n\t"
        "v_mov_b32_dpp v182, v180 quad_perm:[1,0,3,2] row_mask:0xf bank_mask:0xf\n\t"
        "v_mov_b32_dpp v183, v180 quad_perm:[3,3,3,3] row_mask:0xf bank_mask:0xf\n\t"
        "s_nop 2\n\t"
        "v_fma_f32 v177, v182, v177, v181\n\t"     // c_B
        "v_mul_f32 v180, 0x4038aa3b, v177\n\t"
        "v_exp_f32 v180, v180\n\t"
        "s_nop 1\n\t"
        "v_add_f32 v180, 1.0, v180\n\t"
        "v_rcp_f32 v180, v180\n\t"
        "s_nop 1\n\t"
        "v_fma_f32 v180, -2.0, v180, 1.0\n\t"
        "v_mul_f32 v179, v183, v180\n\t"           // hn_B
        "s_mov_b64 s[22:23], exec\n\t"
        "s_mov_b64 exec, s[26:27]\n\t"
        "ds_write_b32 v187, v179\n\t"
        "s_mov_b64 exec, s[22:23]\n\t"
        "s_waitcnt lgkmcnt(0)\n\t"
        "s_barrier\n\t"
        // ---- flush every 64 steps: both batches via m-split ----
        "s_and_b32 s20, s24, 63\n\t"
        "s_cmp_lg_u32 s20, 63\n\t"
        "s_cbranch_scc1 3f\n\t"
        "v_add_u32 v186, 0xffff7000, v186\n\t"     // write base wrap: -36864
        "v_add_u32 v187, 0xffff7000, v187\n\t"
        "global_load_dwordx4 v[160:163], %[offL], %[wlin] offset:0\n\t"
        "global_load_dwordx4 v[164:167], %[offL], %[wlin] offset:16\n\t"
        "global_load_dwordx4 v[168:171], %[offL], %[wlin] offset:32\n\t"
        "global_load_dwordx4 v[172:175], %[offL], %[wlin] offset:48\n\t"
        "global_load_dwordx4 v[204:207], %[offL], %[wlin] offset:64\n\t"
        "global_load_dwordx4 v[208:211], %[offL], %[wlin] offset:80\n\t"
        "global_load_dwordx4 v[212:215], %[offL], %[wlin] offset:96\n\t"
        "global_load_dwordx4 v[216:219], %[offL], %[wlin] offset:112\n\t"
        "ds_read_b128 v[0:3],   v189\n\t"
        "ds_read_b128 v[4:7],   v189 offset:16\n\t"
        "ds_read_b128 v[8:11],  v189 offset:32\n\t"
        "ds_read_b128 v[12:15], v189 offset:48\n\t"
        "ds_read_b128 v[16:19], v189 offset:64\n\t"
        "ds_read_b128 v[20:23], v189 offset:80\n\t"
        "ds_read_b128 v[24:27], v189 offset:96\n\t"
        "ds_read_b128 v[28:31], v189 offset:112\n\t"
        "v_mov_b32 v180, 0\n\t"
        "s_waitcnt vmcnt(0) lgkmcnt(0)\n\t"
        ".set K_I, 0\n"
        ".rept 16\n"
        " v_fma_f32 v180, v[0+K_I], v[160+K_I], v180\n"
        " .set K_I, K_I+1\n"
        ".endr\n"
        ".set K_I, 0\n"
        ".rept 16\n"
        " v_fma_f32 v180, v[16+K_I], v[204+K_I], v180\n"
        " .set K_I, K_I+1\n"
        ".endr\n"
        "s_nop 1\n\t"
        "v_add_f32_dpp v180, v180, v180 quad_perm:[1,0,3,2] row_mask:0xf bank_mask:0xf\n\t"
        "s_nop 1\n\t"
        "v_add_f32_dpp v180, v180, v180 quad_perm:[2,3,0,1] row_mask:0xf bank_mask:0xf\n\t"
        "v_add_f32 v180, %[blinS], v180\n\t"       // + b_lin (SGPR src0)
        "v_add_u32 v192, s28, v191\n\t"            // out byte = base + jO
        "s_mov_b64 s[22:23], exec\n\t"
        "s_mov_b64 exec, s[26:27]\n\t"
        "global_store_dword v192, v180, %[outp]\n\t"
        "s_mov_b64 exec, s[22:23]\n\t"
        "s_add_u32 s28, s28, 0x10000\n\t"          // out base += 64*256*4
        "s_barrier\n\t"                             // protect hist vs next iter
        "3:\n\t"
        "s_add_i32 s24, s24, 1\n\t"
        "s_cmp_lt_i32 s24, 2048\n\t"
        "s_cbranch_scc1 1b\n\t"
        :
        : [off0]"v"(off0), [off1]"v"(off1), [off2]"v"(off2), [off3]"v"(off3),
          [offL]"v"(offL), [whh]"s"(W_hh), [wlin]"s"(W_lin), [outp]"s"(out),
          [wA]"v"(wihA), [wB]"v"(wihB), [wC]"v"(wihC), [wD]"v"(wihD),
          [b0]"v"(b0s), [b1]"v"(b1s), [b2]"v"(b2s), [b3]"v"(b3s),
          [sc0]"v"(sc0), [sc1]"v"(sc1), [sc2]"v"(sc2), [sc3]"v"(sc3),
          [ca]"v"(caq), [cb]"v"(cbq),
          [blinS]"s"(blin), [c0A]"v"(cA), [c0B]"v"(cB),
          [vR]"v"(vR0), [hW]"v"(hW0), [vD]"v"(vD0), [fR]"v"(fR0),
          [jO]"v"(jO0), [oA]"s"(oA0)
        : "memory", "scc", "vcc",
          "s20","s21","s22","s23","s24","s25","s26","s27","s28","s29",
          "v0","v1","v2","v3","v4","v5","v6","v7","v8","v9",
          "v10","v11","v12","v13","v14","v15","v16","v17","v18","v19",
          "v20","v21","v22","v23","v24","v25","v26","v27","v28","v29",
          "v30","v31","v32","v33","v34","v35","v36","v37","v38","v39",
          "v40","v41","v42","v43","v44","v45","v46","v47","v48","v49",
          "v50","v51","v52","v53","v54","v55","v56","v57","v58","v59",
          "v60","v61","v62","v63","v64","v65","v66","v67","v68","v69",
          "v70","v71","v72","v73","v74","v75","v76","v77","v78","v79",
          "v80","v81","v82","v83","v84","v85","v86","v87","v88","v89",
          "v90","v91","v92","v93","v94","v95","v96","v97","v98","v99",
          "v100","v101","v102","v103","v104","v105","v106","v107","v108","v109",
          "v110","v111","v112","v113","v114","v115","v116","v117","v118","v119",
          "v120","v121","v122","v123","v124","v125","v126","v127","v128","v129",
          "v130","v131","v132","v133","v134","v135","v136","v137","v138","v139",
          "v140","v141","v142","v143","v144","v145","v146","v147","v148","v149",
          "v150","v151","v152","v153","v154","v155","v156","v157","v158","v159",
          "v160","v161","v162","v163","v164","v165","v166","v167","v168","v169",
          "v170","v171","v172","v173","v174","v175","v176","v177","v178","v179",
          "v180","v181","v182","v183","v184","v185","v186","v187","v188","v189",
          "v190","v191","v192","v193","v194","v195","v196","v197","v198","v199",
          "v200","v201","v202","v203","v204","v205","v206","v207","v208","v209",
          "v210","v211","v212","v213","v214","v215","v216","v217","v218","v219");
    // no C epilogue: flush at t=2047 covers out[1984..2047]
}

extern "C" void kernel_launch(void* const* d_in, const int* in_sizes, int n_in,
                              void* d_out, int out_size, void* d_ws, size_t ws_size,
                              hipStream_t stream) {
    // inputs: 0 input (unused), 1 label, 2 h0, 3 W_ih, 4 W_hh,
    //         5 b_ih, 6 b_hh, 7 W_lin, 8 b_lin
    const int*   label = (const int*)  d_in[1];
    const float* h0    = (const float*)d_in[2];
    const float* W_ih  = (const float*)d_in[3];
    const float* W_hh  = (const float*)d_in[4];
    const float* b_ih  = (const float*)d_in[5];
    const float* b_hh  = (const float*)d_in[6];
    const float* W_lin = (const float*)d_in[7];
    const float* b_lin = (const float*)d_in[8];
    float* out = (float*)d_out;

    lstm_seq_kernel<<<dim3(BATCH / 2), dim3(512), 0, stream>>>(
        label, h0, W_ih, W_hh, b_ih, b_hh, W_lin, b_lin, out);
}

// Round 5
// 1323.512 us; speedup vs baseline: 1.5163x; 1.5163x over previous
//
#include <hip/hip_runtime.h>
#include <math.h>

// Problem constants: T=2048, B=256, H=128, IN_DIM=1, NUM_DATA=4096
#define T_STEPS 2048
#define BATCH   256
#define HDIM    128

__device__ __forceinline__ float fast_rcp(float x) { return __builtin_amdgcn_rcpf(x); }
__device__ __forceinline__ float sigmoid_f(float x) { return fast_rcp(1.0f + __expf(-x)); }
__device__ __forceinline__ float tanh_f(float x) {
    float e = __expf(2.0f * x);
    return 1.0f - 2.0f * fast_rcp(e + 1.0f);
}

#define REP4(M) M(0) M(1) M(2) M(3)

// R25 = R24 resubmission (Round-4 bench died at container acquire -- same
// infra signature as Round 1, which ran cleanly on resubmit). R24: back to
// 1 batch/block on 256 blocks (R23's 2-batch/block halved CU count for only
// 15%/step gain -- lockstep chains can't hide lockstep stalls). NEW: 1024
// threads/block = 16 waves = 4 waves/SIMD (vs R22's 2).
// Thread (m,s,q): row m=((tid>>4)<<1)|((tid>>2)&1), K-half s=(tid>>3)&1,
// gate-quad q=tid&3; each thread covers a 16-elem K-chunk (64s+16q..+15).
// Aggregate GEMV issue/SIMD and LDS instr count/CU are UNCHANGED vs R22;
// the extra waves exist purely to fill each other's ds-latency / lgkm /
// activation-chain stalls. Reduction = quad gate-XOR butterfly (as R21/22)
// + one row_ror:8 DPP for the s-sum. Bias is now added AFTER the butterfly
// (one v_add with per-lane pre-scaled bias) instead of seeded /4 into the
// accumulators -- frees the seed pairs to fit the <=128-VGPR budget that a
// 16-wave block requires (clobber v0..v101 + 22 v-inputs = 124).
// Register map: h/flush-slot v[0:15], weights v[16:79] (16/slot),
// acc pairs v[80:87], zero seed v[88:89] (re-zeroed after flush),
// tail tmps v90-94, rd v96, wr v97, c v98, hn v99, flush acc v100,
// outaddr v101; flush W_lin v[80:95].
__global__ __launch_bounds__(1024, 4)
void lstm_seq_kernel(const int*   __restrict__ label,
                     const float* __restrict__ h0,     // (1, 4096, 128)
                     const float* __restrict__ W_ih,   // (512, 1)
                     const float* __restrict__ W_hh,   // (512, 128)
                     const float* __restrict__ b_ih,   // (512,)
                     const float* __restrict__ b_hh,   // (512,)
                     const float* __restrict__ W_lin,  // (1, 128)
                     const float* __restrict__ b_lin,  // (1,)
                     float*       __restrict__ out)    // (T, B, 1)
{
    const int tid   = threadIdx.x;
    const int batch = blockIdx.x;
    const int q = tid & 3;                      // gate-quad position
    const int s = (tid >> 3) & 1;               // K-half
    const int m = ((tid >> 4) << 1) | ((tid >> 2) & 1);   // h row 0..127

    const int ri = m, rf = m + 128, rg = m + 256, ro = m + 384;
    const int cb4 = 16 * s + 4 * q;             // float4 idx of chunk in a row

    // 128 slots x 144 words = 73728 B. Slot k holds h_state_{k+1}.
    // Slot 127 doubles as h_init scratch for the C prologue.
    __shared__ __attribute__((aligned(16))) float hist[128 * 144];

    const float4* W4 = (const float4*)W_hh;
    const float4* L4 = (const float4*)W_lin;

    // ---- C-side load + fold (used only for step 0, UNSCALED) ----
    #define DECL_W(i) \
        float4 wi##i = W4[ri * 32 + cb4 + (i)]; \
        float4 wf##i = W4[rf * 32 + cb4 + (i)]; \
        float4 wg##i = W4[rg * 32 + cb4 + (i)]; \
        float4 wo##i = W4[ro * 32 + cb4 + (i)];
    REP4(DECL_W)

    const float wih_i = W_ih[ri], wih_f = W_ih[rf];
    const float wih_g = W_ih[rg], wih_o = W_ih[ro];
    const float blin  = b_lin[0];

    const float bi_ = b_ih[ri] + b_hh[ri] + wih_i * blin;
    const float bf_ = b_ih[rf] + b_hh[rf] + wih_f * blin;
    const float bg_ = b_ih[rg] + b_hh[rg] + wih_g * blin;
    const float bo_ = b_ih[ro] + b_hh[ro] + wih_o * blin;

    // exp2 pre-scale constants, BIT-IDENTICAL to asm literals:
    //   -log2e = 0xBFB8AA3B ; 2log2e = 0x4038AA3B
    const float SNEG = -0x1.715476p+0f;
    const float SG   =  0x1.715476p+1f;

    // per-lane FULL scaled bias of the lane's own gate (added post-butterfly)
    const float bq = (q==0) ? bi_*SNEG : (q==1) ? bf_*SNEG
                   : (q==2) ? bg_*SG   : bo_*SNEG;

    // per-slot W_ih scalars for the fold: slot p holds gate (q^p)
    const float wihA = (q==0)?wih_i:(q==1)?wih_f:(q==2)?wih_g:wih_o;
    const float wihB = (q==0)?wih_f:(q==1)?wih_i:(q==2)?wih_o:wih_g;
    const float wihC = (q==0)?wih_g:(q==1)?wih_o:(q==2)?wih_i:wih_f;
    const float wihD = (q==0)?wih_o:(q==1)?wih_g:(q==2)?wih_f:wih_i;
    // per-slot exp2 pre-scales: gate 2 (g) gets +2log2e, others -log2e
    const float sc0 = ( q    == 2) ? SG : SNEG;
    const float sc1 = ((q^1) == 2) ? SG : SNEG;
    const float sc2 = ((q^2) == 2) ? SG : SNEG;
    const float sc3 = ((q^3) == 2) ? SG : SNEG;
    // per-lane activation finisher: sigmoid a=r ; tanh a=-2r+1
    const float caq = (q==2) ? -2.0f : 1.0f;
    const float cbq = (q==2) ?  1.0f : 0.0f;

    #define FOLD_W(i) { float4 lv = L4[cb4 + (i)]; \
        wi##i.x = fmaf(wih_i, lv.x, wi##i.x); wi##i.y = fmaf(wih_i, lv.y, wi##i.y); \
        wi##i.z = fmaf(wih_i, lv.z, wi##i.z); wi##i.w = fmaf(wih_i, lv.w, wi##i.w); \
        wf##i.x = fmaf(wih_f, lv.x, wf##i.x); wf##i.y = fmaf(wih_f, lv.y, wf##i.y); \
        wf##i.z = fmaf(wih_f, lv.z, wf##i.z); wf##i.w = fmaf(wih_f, lv.w, wf##i.w); \
        wg##i.x = fmaf(wih_g, lv.x, wg##i.x); wg##i.y = fmaf(wih_g, lv.y, wg##i.y); \
        wg##i.z = fmaf(wih_g, lv.z, wg##i.z); wg##i.w = fmaf(wih_g, lv.w, wg##i.w); \
        wo##i.x = fmaf(wih_o, lv.x, wo##i.x); wo##i.y = fmaf(wih_o, lv.y, wo##i.y); \
        wo##i.z = fmaf(wih_o, lv.z, wo##i.z); wo##i.w = fmaf(wih_o, lv.w, wo##i.w); }
    REP4(FOLD_W)

    const int   lane  = tid & 63;
    const int   ya0w  = lane + ((lane >> 5) << 2);  // word of h[lane] in a slot
    const float wl_a  = W_lin[lane];
    const float wl_b  = W_lin[lane + 64];
    const int   hword = m + ((m >> 5) << 2);        // element word in a slot

    // ---- init h into slot 127 (scratch; overwritten at t=127) ----
    float* slotI = &hist[144 * 127];
    if (tid < HDIM) slotI[tid + ((tid >> 5) << 2)] = h0[label[batch] * HDIM + tid];
    __syncthreads();

    // y_init (uniform across waves) for the t=0 bias correction
    float p0 = slotI[ya0w] * wl_a + slotI[ya0w + 72] * wl_b;
    #pragma unroll
    for (int off = 1; off < 64; off <<= 1) p0 += __shfl_xor(p0, off, 64);
    const float y0 = p0 + blin;

    const float cbi = bi_ - wih_i * y0;
    const float cbf = bf_ - wih_f * y0;
    const float cbg = bg_ - wih_g * y0;
    const float cbo = bo_ - wih_o * y0;

    // ---- step 0 in C: read slot 127 (init), write state 1 into slot 0 ----
    const float4* hs = (const float4*)slotI;
    const int hb4 = 18 * s + 4 * q + (q >> 1);      // chunk float4 idx in slot
    float ai = 0.f, af = 0.f, ag = 0.f, ao = 0.f;
    #define DOT4(i) { float4 hv = hs[hb4 + (i)]; \
        ai = fmaf(hv.x, wi##i.x, ai); ai = fmaf(hv.y, wi##i.y, ai); \
        ai = fmaf(hv.z, wi##i.z, ai); ai = fmaf(hv.w, wi##i.w, ai); \
        af = fmaf(hv.x, wf##i.x, af); af = fmaf(hv.y, wf##i.y, af); \
        af = fmaf(hv.z, wf##i.z, af); af = fmaf(hv.w, wf##i.w, af); \
        ag = fmaf(hv.x, wg##i.x, ag); ag = fmaf(hv.y, wg##i.y, ag); \
        ag = fmaf(hv.z, wg##i.z, ag); ag = fmaf(hv.w, wg##i.w, ag); \
        ao = fmaf(hv.x, wo##i.x, ao); ao = fmaf(hv.y, wo##i.y, ao); \
        ao = fmaf(hv.z, wo##i.z, ao); ao = fmaf(hv.w, wo##i.w, ao); }
    REP4(DOT4)
    // sum over the 8 lanes of row m: q bits (xor1,xor2) and s bit (xor8)
    ai += __shfl_xor(ai, 1, 64); af += __shfl_xor(af, 1, 64);
    ag += __shfl_xor(ag, 1, 64); ao += __shfl_xor(ao, 1, 64);
    ai += __shfl_xor(ai, 2, 64); af += __shfl_xor(af, 2, 64);
    ag += __shfl_xor(ag, 2, 64); ao += __shfl_xor(ao, 2, 64);
    ai += __shfl_xor(ai, 8, 64); af += __shfl_xor(af, 8, 64);
    ag += __shfl_xor(ag, 8, 64); ao += __shfl_xor(ao, 8, 64);
    const float iv0 = sigmoid_f(ai + cbi);
    const float fv0 = sigmoid_f(af + cbf);
    const float gv0 = tanh_f  (ag + cbg);
    const float ov0 = sigmoid_f(ao + cbo);
    float c = iv0 * gv0;                 // c_prev = 0
    const float hn0 = ov0 * tanh_f(c);
    if (q == 0 && s == 0) hist[hword] = hn0;   // slot 0 = state 1
    __syncthreads();

    // ---- asm operand prep ----
    const unsigned histB = (unsigned)(unsigned long long)(&hist[0]);
    const unsigned chunkoff = 288u*(unsigned)s + 64u*(unsigned)q + 16u*(unsigned)(q>>1);
    const unsigned vR0 = histB + chunkoff;                 // slot0 chunk read
    const unsigned hW0 = histB + 4u * (unsigned)hword;     // write base (advance-then-write)
    const unsigned vD0 = chunkoff - 4u * (unsigned)hword;  // rd(t) = wr(t) + vD -> slot t
    const unsigned fR0 = histB + 576u * (unsigned)m + chunkoff; // flush: slot m, own chunk
    const unsigned jO0 = 1024u * (unsigned)m;              // out byte: row m within window
    const unsigned oA0 = 4u * (unsigned)batch;             // out[0] byte
    // slot p <- weight row (m + 128*(q^p)), chunk (s,q)
    const unsigned off0 = (unsigned)((m + 128 * (q    )) * 512 + 256*s + 64*q);
    const unsigned off1 = (unsigned)((m + 128 * (q ^ 1)) * 512 + 256*s + 64*q);
    const unsigned off2 = (unsigned)((m + 128 * (q ^ 2)) * 512 + 256*s + 64*q);
    const unsigned off3 = (unsigned)((m + 128 * (q ^ 3)) * 512 + 256*s + 64*q);
    const unsigned offL = (unsigned)(256*s + 64*q);

    asm volatile(
        // ---------------- prologue ----------------
        "v_mov_b32 v96, %[vR]\n\t"
        "v_mov_b32 v97, %[hW]\n\t"
        "v_mov_b32 v98, %[c0]\n\t"
        "v_mov_b32 v88, 0\n\t"
        "v_mov_b32 v89, 0\n\t"
        // store mask: s==0 && q==0 lanes (lane%16 in {0,4})
        "s_mov_b32 s26, 0x00110011\n\t"
        "s_mov_b32 s27, 0x00110011\n\t"
        "s_mov_b32 s28, %[oA]\n\t"
        // weights: 4x dwordx4 per slot (gate-XOR-permuted rows, chunk (s,q))
        "global_load_dwordx4 v[16:19], %[off0], %[whh] offset:0\n\t"
        "global_load_dwordx4 v[20:23], %[off0], %[whh] offset:16\n\t"
        "global_load_dwordx4 v[24:27], %[off0], %[whh] offset:32\n\t"
        "global_load_dwordx4 v[28:31], %[off0], %[whh] offset:48\n\t"
        "global_load_dwordx4 v[32:35], %[off1], %[whh] offset:0\n\t"
        "global_load_dwordx4 v[36:39], %[off1], %[whh] offset:16\n\t"
        "global_load_dwordx4 v[40:43], %[off1], %[whh] offset:32\n\t"
        "global_load_dwordx4 v[44:47], %[off1], %[whh] offset:48\n\t"
        "global_load_dwordx4 v[48:51], %[off2], %[whh] offset:0\n\t"
        "global_load_dwordx4 v[52:55], %[off2], %[whh] offset:16\n\t"
        "global_load_dwordx4 v[56:59], %[off2], %[whh] offset:32\n\t"
        "global_load_dwordx4 v[60:63], %[off2], %[whh] offset:48\n\t"
        "global_load_dwordx4 v[64:67], %[off3], %[whh] offset:0\n\t"
        "global_load_dwordx4 v[68:71], %[off3], %[whh] offset:16\n\t"
        "global_load_dwordx4 v[72:75], %[off3], %[whh] offset:32\n\t"
        "global_load_dwordx4 v[76:79], %[off3], %[whh] offset:48\n\t"
        // W_lin chunk (temp, consumed by fold) -> v[0:15]
        "global_load_dwordx4 v[0:3],   %[offL], %[wlin] offset:0\n\t"
        "global_load_dwordx4 v[4:7],   %[offL], %[wlin] offset:16\n\t"
        "global_load_dwordx4 v[8:11],  %[offL], %[wlin] offset:32\n\t"
        "global_load_dwordx4 v[12:15], %[offL], %[wlin] offset:48\n\t"
        "s_waitcnt vmcnt(0)\n\t"
        // fold W' = W + wih(q^p)*W_lin, then exp2 pre-scale
        ".set K_I, 0\n"
        ".rept 16\n"
        " v_fma_f32 v[16+K_I], %[wA], v[K_I], v[16+K_I]\n"
        " v_fma_f32 v[32+K_I], %[wB], v[K_I], v[32+K_I]\n"
        " v_fma_f32 v[48+K_I], %[wC], v[K_I], v[48+K_I]\n"
        " v_fma_f32 v[64+K_I], %[wD], v[K_I], v[64+K_I]\n"
        " .set K_I, K_I+1\n"
        ".endr\n"
        ".set K_I, 0\n"
        ".rept 16\n"
        " v_mul_f32 v[16+K_I], %[sc0], v[16+K_I]\n"
        " v_mul_f32 v[32+K_I], %[sc1], v[32+K_I]\n"
        " v_mul_f32 v[48+K_I], %[sc2], v[48+K_I]\n"
        " v_mul_f32 v[64+K_I], %[sc3], v[64+K_I]\n"
        " .set K_I, K_I+1\n"
        ".endr\n"
        "s_movk_i32 s24, 1\n\t"
        // ---------------- main loop: t = 1 .. 2047 ----------------
        "1:\n\t"
        // h chunk: 4x b128 broadcast reads from slot t-1
        "ds_read_b128 v[0:3],   v96\n\t"
        "ds_read_b128 v[4:7],   v96 offset:16\n\t"
        "ds_read_b128 v[8:11],  v96 offset:32\n\t"
        "ds_read_b128 v[12:15], v96 offset:48\n\t"
        // ---- packed GEMV: 8 pair-groups x 4 slots, staggered lgkm ----
        "s_waitcnt lgkmcnt(2)\n\t"
        "v_pk_fma_f32 v[80:81], v[0:1], v[16:17], v[88:89]\n\t"
        "v_pk_fma_f32 v[82:83], v[0:1], v[32:33], v[88:89]\n\t"
        "v_pk_fma_f32 v[84:85], v[0:1], v[48:49], v[88:89]\n\t"
        "v_pk_fma_f32 v[86:87], v[0:1], v[64:65], v[88:89]\n\t"
        ".set K_I, 2\n"
        ".rept 3\n"
        " v_pk_fma_f32 v[80:81], v[K_I:K_I+1], v[16+K_I:17+K_I], v[80:81]\n"
        " v_pk_fma_f32 v[82:83], v[K_I:K_I+1], v[32+K_I:33+K_I], v[82:83]\n"
        " v_pk_fma_f32 v[84:85], v[K_I:K_I+1], v[48+K_I:49+K_I], v[84:85]\n"
        " v_pk_fma_f32 v[86:87], v[K_I:K_I+1], v[64+K_I:65+K_I], v[86:87]\n"
        " .set K_I, K_I+2\n"
        ".endr\n"
        "s_waitcnt lgkmcnt(0)\n\t"
        ".rept 4\n"
        " v_pk_fma_f32 v[80:81], v[K_I:K_I+1], v[16+K_I:17+K_I], v[80:81]\n"
        " v_pk_fma_f32 v[82:83], v[K_I:K_I+1], v[32+K_I:33+K_I], v[82:83]\n"
        " v_pk_fma_f32 v[84:85], v[K_I:K_I+1], v[48+K_I:49+K_I], v[84:85]\n"
        " v_pk_fma_f32 v[86:87], v[K_I:K_I+1], v[64+K_I:65+K_I], v[86:87]\n"
        " .set K_I, K_I+2\n"
        ".endr\n"
        // ---- collapse lo+hi: slot sums (slot p = gate p^q, chunk (s,q)) ----
        "v_add_f32 v80, v80, v81\n\t"
        "v_add_f32 v81, v82, v83\n\t"
        "v_add_f32 v84, v84, v85\n\t"
        "v_add_f32 v85, v86, v87\n\t"
        // ---- gate butterfly (quad) then s-sum (row_ror:8) ----
        "s_nop 1\n\t"
        "v_add_f32_dpp v80, v81, v80 quad_perm:[1,0,3,2] row_mask:0xf bank_mask:0xf\n\t"
        "v_add_f32_dpp v84, v85, v84 quad_perm:[1,0,3,2] row_mask:0xf bank_mask:0xf\n\t"
        // ptr advance fills the DPP gap: wr -> slot t, rd -> slot t (next read)
        "v_add_u32 v97, 0x240, v97\n\t"
        "v_add_u32 v96, v97, %[vD]\n\t"
        "v_add_f32_dpp v80, v84, v80 quad_perm:[2,3,0,1] row_mask:0xf bank_mask:0xf\n\t"
        "s_nop 1\n\t"
        "v_add_f32_dpp v80, v80, v80 row_ror:8 row_mask:0xf bank_mask:0xf\n\t"
        // ---- + scaled bias, single activation path ----
        "s_nop 2\n\t"
        "v_add_f32 v80, %[bq], v80\n\t"
        "v_exp_f32 v80, v80\n\t"
        "s_nop 1\n\t"
        "v_add_f32 v80, 1.0, v80\n\t"
        "v_rcp_f32 v80, v80\n\t"
        "s_nop 1\n\t"
        "v_fma_f32 v90, %[ca], v80, %[cb]\n\t"   // a = sigmoid/tanh of gate q
        // ---- quad redistribute: ig, f, o ----
        "s_nop 3\n\t"
        "v_mul_f32_dpp v91, v90, v90 quad_perm:[2,3,0,1] row_mask:0xf bank_mask:0xf\n\t"
        "v_mov_b32_dpp v92, v90 quad_perm:[1,0,3,2] row_mask:0xf bank_mask:0xf\n\t"
        "v_mov_b32_dpp v93, v90 quad_perm:[3,3,3,3] row_mask:0xf bank_mask:0xf\n\t"
        "s_nop 2\n\t"
        "v_fma_f32 v98, v92, v98, v91\n\t"       // c = f*c + i*g (q==0 exact)
        // tanh(c)
        "v_mul_f32 v94, 0x4038aa3b, v98\n\t"
        "v_exp_f32 v94, v94\n\t"
        "s_nop 1\n\t"
        "v_add_f32 v94, 1.0, v94\n\t"
        "v_rcp_f32 v94, v94\n\t"
        "s_nop 1\n\t"
        "v_fma_f32 v94, -2.0, v94, 1.0\n\t"
        "v_mul_f32 v99, v93, v94\n\t"            // hn = o * tanh(c)
        // publish h into ring slot t (s==0,q==0 lanes; v97 already advanced)
        "s_mov_b64 s[22:23], exec\n\t"
        "s_mov_b64 exec, s[26:27]\n\t"
        "ds_write_b32 v97, v99\n\t"
        "s_mov_b64 exec, s[22:23]\n\t"
        "s_waitcnt lgkmcnt(0)\n\t"
        "s_barrier\n\t"
        // ---- flush every 128 steps: out[...] = hist[slot m].W_lin + blin ----
        "s_and_b32 s20, s24, 127\n\t"
        "s_cmp_lg_u32 s20, 127\n\t"
        "s_cbranch_scc1 3f\n\t"
        "v_add_u32 v97, 0xfffee000, v97\n\t"     // write base wrap: -73728
        "global_load_dwordx4 v[80:83], %[offL], %[wlin] offset:0\n\t"
        "global_load_dwordx4 v[84:87], %[offL], %[wlin] offset:16\n\t"
        "global_load_dwordx4 v[88:91], %[offL], %[wlin] offset:32\n\t"
        "global_load_dwordx4 v[92:95], %[offL], %[wlin] offset:48\n\t"
        "ds_read_b128 v[0:3],   %[fR]\n\t"
        "ds_read_b128 v[4:7],   %[fR] offset:16\n\t"
        "ds_read_b128 v[8:11],  %[fR] offset:32\n\t"
        "ds_read_b128 v[12:15], %[fR] offset:48\n\t"
        "v_mov_b32 v100, 0\n\t"
        "s_waitcnt vmcnt(0) lgkmcnt(0)\n\t"
        ".set K_I, 0\n"
        ".rept 16\n"
        " v_fma_f32 v100, v[K_I], v[80+K_I], v100\n"
        " .set K_I, K_I+1\n"
        ".endr\n"
        "s_nop 1\n\t"
        "v_add_f32_dpp v100, v100, v100 quad_perm:[1,0,3,2] row_mask:0xf bank_mask:0xf\n\t"
        "s_nop 1\n\t"
        "v_add_f32_dpp v100, v100, v100 quad_perm:[2,3,0,1] row_mask:0xf bank_mask:0xf\n\t"
        "s_nop 1\n\t"
        "v_add_f32_dpp v100, v100, v100 row_ror:8 row_mask:0xf bank_mask:0xf\n\t"
        "s_nop 2\n\t"
        "v_add_f32 v100, %[blinS], v100\n\t"     // + b_lin
        "v_add_u32 v101, s28, %[jO]\n\t"         // out byte = base + m*1024
        "s_mov_b64 s[22:23], exec\n\t"
        "s_mov_b64 exec, s[26:27]\n\t"
        "global_store_dword v101, v100, %[outp]\n\t"
        "s_mov_b64 exec, s[22:23]\n\t"
        "s_add_u32 s28, s28, 0x20000\n\t"        // out base += 128*256*4
        "v_mov_b32 v88, 0\n\t"                   // re-zero pk seed pair
        "v_mov_b32 v89, 0\n\t"
        "s_barrier\n\t"                           // protect hist vs next iter
        "3:\n\t"
        "s_add_i32 s24, s24, 1\n\t"
        "s_cmp_lt_i32 s24, 2048\n\t"
        "s_cbranch_scc1 1b\n\t"
        :
        : [off0]"v"(off0), [off1]"v"(off1), [off2]"v"(off2), [off3]"v"(off3),
          [offL]"v"(offL), [whh]"s"(W_hh), [wlin]"s"(W_lin), [outp]"s"(out),
          [wA]"v"(wihA), [wB]"v"(wihB), [wC]"v"(wihC), [wD]"v"(wihD),
          [sc0]"v"(sc0), [sc1]"v"(sc1), [sc2]"v"(sc2), [sc3]"v"(sc3),
          [bq]"v"(bq), [ca]"v"(caq), [cb]"v"(cbq),
          [blinS]"s"(blin), [c0]"v"(c),
          [vR]"v"(vR0), [hW]"v"(hW0), [vD]"v"(vD0), [fR]"v"(fR0),
          [jO]"v"(jO0), [oA]"s"(oA0)
        : "memory", "scc", "vcc",
          "s20","s21","s22","s23","s24","s25","s26","s27","s28",
          "v0","v1","v2","v3","v4","v5","v6","v7","v8","v9",
          "v10","v11","v12","v13","v14","v15","v16","v17","v18","v19",
          "v20","v21","v22","v23","v24","v25","v26","v27","v28","v29",
          "v30","v31","v32","v33","v34","v35","v36","v37","v38","v39",
          "v40","v41","v42","v43","v44","v45","v46","v47","v48","v49",
          "v50","v51","v52","v53","v54","v55","v56","v57","v58","v59",
          "v60","v61","v62","v63","v64","v65","v66","v67","v68","v69",
          "v70","v71","v72","v73","v74","v75","v76","v77","v78","v79",
          "v80","v81","v82","v83","v84","v85","v86","v87","v88","v89",
          "v90","v91","v92","v93","v94","v95","v96","v97","v98","v99",
          "v100","v101");
    // no C epilogue: flush k=15 covers out[1920..2047]
}

extern "C" void kernel_launch(void* const* d_in, const int* in_sizes, int n_in,
                              void* d_out, int out_size, void* d_ws, size_t ws_size,
                              hipStream_t stream) {
    // inputs: 0 input (unused), 1 label, 2 h0, 3 W_ih, 4 W_hh,
    //         5 b_ih, 6 b_hh, 7 W_lin, 8 b_lin
    const int*   label = (const int*)  d_in[1];
    const float* h0    = (const float*)d_in[2];
    const float* W_ih  = (const float*)d_in[3];
    const float* W_hh  = (const float*)d_in[4];
    const float* b_ih  = (const float*)d_in[5];
    const float* b_hh  = (const float*)d_in[6];
    const float* W_lin = (const float*)d_in[7];
    const float* b_lin = (const float*)d_in[8];
    float* out = (float*)d_out;

    lstm_seq_kernel<<<dim3(BATCH), dim3(1024), 0, stream>>>(
        label, h0, W_ih, W_hh, b_ih, b_hh, W_lin, b_lin, out);
}

// Round 8
// 1266.543 us; speedup vs baseline: 1.5845x; 1.0450x over previous
//
#include <hip/hip_runtime.h>
#include <math.h>

// Problem constants: T=2048, B=256, H=128, IN_DIM=1, NUM_DATA=4096
#define T_STEPS 2048
#define BATCH   256
#define HDIM    128

__device__ __forceinline__ float fast_rcp(float x) { return __builtin_amdgcn_rcpf(x); }
__device__ __forceinline__ float sigmoid_f(float x) { return fast_rcp(1.0f + __expf(-x)); }
__device__ __forceinline__ float tanh_f(float x) {
    float e = __expf(2.0f * x);
    return 1.0f - 2.0f * fast_rcp(e + 1.0f);
}

#define REP8(M) M(0) M(1) M(2) M(3) M(4) M(5) M(6) M(7)

// R28 = R27 with the FLUSH PAIRING BUG fixed. R27 moved the per-lane K
// decomposition to crew-chunk order {64crew+16q..+15} u {64(1-crew)+16q..+15}
// (weights, W_lin fold, h reads all chunk-ordered) but the flush kept the
// OLD contiguous-quarter read address (elements 32q..) while dotting against
// chunk-ordered W_lin regs -> mispaired dot product, absmax 4.8e-2. The
// h-state recurrence itself was correct. Fix: flush reads own-chunk at
// slot + ownoff and other-chunk at +s30, matching v[188:219] order.
//
// Structure (unchanged from R27): crew flag sync replaces the per-step
// s_barrier. Crews alpha=waves 0-3 (h elems 0-63), beta=waves 4-7 (64-127);
// waves w,w+4 share a SIMD. Own-chunk GEMV guarded by sibling flags >= t-1;
// foreign chunk guarded by foreign flags (checked while own GEMV runs).
// Publish: h-write then flags[w]=t (DS pipe in-order per wave). Crews run
// ~half a step out of phase (beta-only s_nop seed each window) so one
// wave's serial activation chain overlaps its SIMD partner's dense GEMV.
// Flush every 128 steps keeps full s_barrier + re-seeds skew. Spins have a
// 16K-iteration bailout.
__global__ __launch_bounds__(512, 2)
void lstm_seq_kernel(const int*   __restrict__ label,
                     const float* __restrict__ h0,     // (1, 4096, 128)
                     const float* __restrict__ W_ih,   // (512, 1)
                     const float* __restrict__ W_hh,   // (512, 128)
                     const float* __restrict__ b_ih,   // (512,)
                     const float* __restrict__ b_hh,   // (512,)
                     const float* __restrict__ W_lin,  // (1, 128)
                     const float* __restrict__ b_lin,  // (1,)
                     float*       __restrict__ out)    // (T, B, 1)
{
    const int tid   = threadIdx.x;
    const int batch = blockIdx.x;
    const int m     = tid >> 2;     // h element 0..127 (also flush t-slot j)
    const int q     = tid & 3;      // chunk selector 0..3
    const int q8    = q * 8;
    const int crew  = tid >> 8;     // 0 = waves 0-3 (elems 0-63), 1 = waves 4-7

    const int ri = m, rf = m + 128, rg = m + 256, ro = m + 384;

    // 128 slots x 144 words = 73728 B + 8 flag words. Slot k = h_state_{k+1}.
    // Slot 127 doubles as h_init scratch for the C prologue.
    __shared__ __attribute__((aligned(64))) float hist[128 * 144 + 8];

    const float4* W4 = (const float4*)W_hh;
    const float4* L4 = (const float4*)W_lin;

    // ---- C-side load + fold (used only for step 0, UNSCALED) ----
    #define DECL_W(i) \
        float4 wi##i = W4[ri * 32 + q8 + (i)]; \
        float4 wf##i = W4[rf * 32 + q8 + (i)]; \
        float4 wg##i = W4[rg * 32 + q8 + (i)]; \
        float4 wo##i = W4[ro * 32 + q8 + (i)];
    REP8(DECL_W)

    const float wih_i = W_ih[ri], wih_f = W_ih[rf];
    const float wih_g = W_ih[rg], wih_o = W_ih[ro];
    const float blin  = b_lin[0];

    const float bi_ = b_ih[ri] + b_hh[ri] + wih_i * blin;
    const float bf_ = b_ih[rf] + b_hh[rf] + wih_f * blin;
    const float bg_ = b_ih[rg] + b_hh[rg] + wih_g * blin;
    const float bo_ = b_ih[ro] + b_hh[ro] + wih_o * blin;

    // scaled quarter-seed biases: s_gate * bias / 4 (bit-identical consts)
    const float SNEG = -0x1.715476p+0f;   // -log2e = 0xBFB8AA3B
    const float SG   =  0x1.715476p+1f;   // 2log2e = 0x4038AA3B
    const float sI  = bi_ * 0.25f * SNEG;
    const float sF  = bf_ * 0.25f * SNEG;
    const float sG_ = bg_ * 0.25f * SG;
    const float sO  = bo_ * 0.25f * SNEG;

    // gate-XOR permutation: slot p on lane q holds gate (p^q)
    const float b0s = (q==0)?sI :(q==1)?sF :(q==2)?sG_:sO;
    const float b1s = (q==0)?sF :(q==1)?sI :(q==2)?sO :sG_;
    const float b2s = (q==0)?sG_:(q==1)?sO :(q==2)?sI :sF;
    const float b3s = (q==0)?sO :(q==1)?sG_:(q==2)?sF :sI;
    const float wihA = (q==0)?wih_i:(q==1)?wih_f:(q==2)?wih_g:wih_o;
    const float wihB = (q==0)?wih_f:(q==1)?wih_i:(q==2)?wih_o:wih_g;
    const float wihC = (q==0)?wih_g:(q==1)?wih_o:(q==2)?wih_i:wih_f;
    const float wihD = (q==0)?wih_o:(q==1)?wih_g:(q==2)?wih_f:wih_i;
    const float sc0 = ( q    == 2) ? SG : SNEG;
    const float sc1 = ((q^1) == 2) ? SG : SNEG;
    const float sc2 = ((q^2) == 2) ? SG : SNEG;
    const float sc3 = ((q^3) == 2) ? SG : SNEG;
    const float caq = (q==2) ? -2.0f : 1.0f;
    const float cbq = (q==2) ?  1.0f : 0.0f;

    #define FOLD_W(i) { float4 lv = L4[q8 + (i)]; \
        wi##i.x = fmaf(wih_i, lv.x, wi##i.x); wi##i.y = fmaf(wih_i, lv.y, wi##i.y); \
        wi##i.z = fmaf(wih_i, lv.z, wi##i.z); wi##i.w = fmaf(wih_i, lv.w, wi##i.w); \
        wf##i.x = fmaf(wih_f, lv.x, wf##i.x); wf##i.y = fmaf(wih_f, lv.y, wf##i.y); \
        wf##i.z = fmaf(wih_f, lv.z, wf##i.z); wf##i.w = fmaf(wih_f, lv.w, wf##i.w); \
        wg##i.x = fmaf(wih_g, lv.x, wg##i.x); wg##i.y = fmaf(wih_g, lv.y, wg##i.y); \
        wg##i.z = fmaf(wih_g, lv.z, wg##i.z); wg##i.w = fmaf(wih_g, lv.w, wg##i.w); \
        wo##i.x = fmaf(wih_o, lv.x, wo##i.x); wo##i.y = fmaf(wih_o, lv.y, wo##i.y); \
        wo##i.z = fmaf(wih_o, lv.z, wo##i.z); wo##i.w = fmaf(wih_o, lv.w, wo##i.w); }
    REP8(FOLD_W)

    const int   lane  = tid & 63;
    const int   ya0w  = lane + ((lane >> 5) << 2);
    const float wl_a  = W_lin[lane];
    const float wl_b  = W_lin[lane + 64];
    const int   hword = m + ((m >> 5) << 2);

    // ---- init: flags = 0, h into slot 127 (scratch) ----
    if (tid < 8) hist[18432 + tid] = 0.0f;          // flag words (bits zero)
    float* slotI = &hist[144 * 127];
    if (tid < HDIM) slotI[tid + ((tid >> 5) << 2)] = h0[label[batch] * HDIM + tid];
    __syncthreads();

    // y_init (uniform across waves) for the t=0 bias correction
    float p0 = slotI[ya0w] * wl_a + slotI[ya0w + 72] * wl_b;
    #pragma unroll
    for (int off = 1; off < 64; off <<= 1) p0 += __shfl_xor(p0, off, 64);
    const float y0 = p0 + blin;

    const float cbi = bi_ - wih_i * y0;
    const float cbf = bf_ - wih_f * y0;
    const float cbg = bg_ - wih_g * y0;
    const float cbo = bo_ - wih_o * y0;

    // ---- step 0 in C: read slot 127 (init), write state 1 into slot 0 ----
    const float4* hq0 = (const float4*)(slotI + 36 * q);
    float ai = 0.f, af = 0.f, ag = 0.f, ao = 0.f;
    #define DOT4(i) { float4 hv = hq0[(i)]; \
        ai = fmaf(hv.x, wi##i.x, ai); ai = fmaf(hv.y, wi##i.y, ai); \
        ai = fmaf(hv.z, wi##i.z, ai); ai = fmaf(hv.w, wi##i.w, ai); \
        af = fmaf(hv.x, wf##i.x, af); af = fmaf(hv.y, wf##i.y, af); \
        af = fmaf(hv.z, wf##i.z, af); af = fmaf(hv.w, wf##i.w, af); \
        ag = fmaf(hv.x, wg##i.x, ag); ag = fmaf(hv.y, wg##i.y, ag); \
        ag = fmaf(hv.z, wg##i.z, ag); ag = fmaf(hv.w, wg##i.w, ag); \
        ao = fmaf(hv.x, wo##i.x, ao); ao = fmaf(hv.y, wo##i.y, ao); \
        ao = fmaf(hv.z, wo##i.z, ao); ao = fmaf(hv.w, wo##i.w, ao); }
    REP8(DOT4)
    ai += __shfl_xor(ai, 1, 64); af += __shfl_xor(af, 1, 64);
    ag += __shfl_xor(ag, 1, 64); ao += __shfl_xor(ao, 1, 64);
    ai += __shfl_xor(ai, 2, 64); af += __shfl_xor(af, 2, 64);
    ag += __shfl_xor(ag, 2, 64); ao += __shfl_xor(ao, 2, 64);
    const float iv0 = sigmoid_f(ai + cbi);
    const float fv0 = sigmoid_f(af + cbf);
    const float gv0 = tanh_f  (ag + cbg);
    const float ov0 = sigmoid_f(ao + cbo);
    float c = iv0 * gv0;                 // c_prev = 0
    const float hn0 = ov0 * tanh_f(c);
    if (q == 0) hist[hword] = hn0;       // slot 0 = state 1
    __syncthreads();

    // ---- asm operand prep ----
    const unsigned histB = (unsigned)(unsigned long long)(&hist[0]);
    // own-crew 16-elem chunk byte offset within a slot (pad-aware):
    // element e0 = 64*crew + 16*q -> byte 4*e0 + 16*(e0>>5)
    const unsigned ownoff = 288u * (unsigned)crew + 64u * (unsigned)q
                          + 16u * (unsigned)(q >> 1);
    const unsigned vR0 = histB + ownoff;                  // slot0 own-chunk read
    const unsigned hW0 = histB + 4u * (unsigned)hword;    // write base (advance-then-write)
    const unsigned vD0 = ownoff - 4u * (unsigned)hword;   // rd(t+1) = wr(t) + vD
    // FLUSH FIX: read own-chunk (matches W_lin v[188:203]); other at +s30.
    const unsigned fR0 = histB + 576u * (unsigned)m + ownoff;
    const unsigned jO0 = 1024u * (unsigned)m;             // out byte: row m of window
    const unsigned vO0 = 4u * (unsigned)batch;            // out[0] byte
    // weight rows (gate-XOR), own chunk first: byte = row*512 + 64q + 256*crew
    const unsigned off0 = (unsigned)((m + 128 * (q    )) * 512 + 64*q + 256*crew);
    const unsigned off1 = (unsigned)((m + 128 * (q ^ 1)) * 512 + 64*q + 256*crew);
    const unsigned off2 = (unsigned)((m + 128 * (q ^ 2)) * 512 + 64*q + 256*crew);
    const unsigned off3 = (unsigned)((m + 128 * (q ^ 3)) * 512 + 64*q + 256*crew);
    const unsigned offL = (unsigned)(64*q + 256*crew);
    // flag addresses
    const unsigned sibF0 = histB + 73728u + 16u * (unsigned)crew + 4u * (unsigned)(lane & 3);
    const unsigned pubF0 = histB + 73728u + 4u * (unsigned)(tid >> 6);
    const unsigned crewv = (unsigned)crew;

    asm volatile(
        // ---------------- prologue: fixed-reg setup ----------------
        "v_mov_b32 v220, %[b0]\n\t"
        "v_mov_b32 v221, 0\n\t"
        "v_mov_b32 v222, %[b1]\n\t"
        "v_mov_b32 v223, 0\n\t"
        "v_mov_b32 v224, %[b2]\n\t"
        "v_mov_b32 v225, 0\n\t"
        "v_mov_b32 v226, %[b3]\n\t"
        "v_mov_b32 v227, 0\n\t"
        "v_mov_b32 v185, %[blin]\n\t"
        "v_mov_b32 v168, %[c0]\n\t"
        "v_mov_b32 v172, %[vR]\n\t"
        "v_mov_b32 v174, %[hW]\n\t"
        "v_mov_b32 v186, %[vD]\n\t"
        "v_mov_b32 v184, %[fR]\n\t"
        "v_mov_b32 v171, %[jO]\n\t"
        "v_mov_b32 v177, %[sibF]\n\t"
        "v_xor_b32 v178, 16, v177\n\t"            // foreign flag addr (flag base 64-aligned)
        "v_mov_b32 v179, %[pubF]\n\t"
        "v_readfirstlane_b32 s29, %[crewv]\n\t"   // crew 0/1
        "s_nop 4\n\t"
        "s_mul_i32 s30, s29, -576\n\t"
        "s_addk_i32 s30, 288\n\t"                 // LDS other-chunk delta: 288-576c
        "s_mul_i32 s31, s29, -512\n\t"
        "s_addk_i32 s31, 256\n\t"                 // global other-chunk delta: 256-512c
        // q==0 store mask
        "s_mov_b32 s26, 0x11111111\n\t"
        "s_mov_b32 s27, 0x11111111\n\t"
        "s_mov_b32 s28, %[vO]\n\t"
        // weights: per slot, own-chunk 4x dwordx4 then other-chunk 4x dwordx4
        "global_load_dwordx4 v[32:35], %[off0], %[whh] offset:0\n\t"
        "global_load_dwordx4 v[36:39], %[off0], %[whh] offset:16\n\t"
        "global_load_dwordx4 v[40:43], %[off0], %[whh] offset:32\n\t"
        "global_load_dwordx4 v[44:47], %[off0], %[whh] offset:48\n\t"
        "v_add_u32 v181, s31, %[off0]\n\t"
        "global_load_dwordx4 v[48:51], v181, %[whh] offset:0\n\t"
        "global_load_dwordx4 v[52:55], v181, %[whh] offset:16\n\t"
        "global_load_dwordx4 v[56:59], v181, %[whh] offset:32\n\t"
        "global_load_dwordx4 v[60:63], v181, %[whh] offset:48\n\t"
        "global_load_dwordx4 v[64:67], %[off1], %[whh] offset:0\n\t"
        "global_load_dwordx4 v[68:71], %[off1], %[whh] offset:16\n\t"
        "global_load_dwordx4 v[72:75], %[off1], %[whh] offset:32\n\t"
        "global_load_dwordx4 v[76:79], %[off1], %[whh] offset:48\n\t"
        "v_add_u32 v181, s31, %[off1]\n\t"
        "global_load_dwordx4 v[80:83], v181, %[whh] offset:0\n\t"
        "global_load_dwordx4 v[84:87], v181, %[whh] offset:16\n\t"
        "global_load_dwordx4 v[88:91], v181, %[whh] offset:32\n\t"
        "global_load_dwordx4 v[92:95], v181, %[whh] offset:48\n\t"
        "global_load_dwordx4 v[96:99], %[off2], %[whh] offset:0\n\t"
        "global_load_dwordx4 v[100:103], %[off2], %[whh] offset:16\n\t"
        "global_load_dwordx4 v[104:107], %[off2], %[whh] offset:32\n\t"
        "global_load_dwordx4 v[108:111], %[off2], %[whh] offset:48\n\t"
        "v_add_u32 v181, s31, %[off2]\n\t"
        "global_load_dwordx4 v[112:115], v181, %[whh] offset:0\n\t"
        "global_load_dwordx4 v[116:119], v181, %[whh] offset:16\n\t"
        "global_load_dwordx4 v[120:123], v181, %[whh] offset:32\n\t"
        "global_load_dwordx4 v[124:127], v181, %[whh] offset:48\n\t"
        "global_load_dwordx4 v[128:131], %[off3], %[whh] offset:0\n\t"
        "global_load_dwordx4 v[132:135], %[off3], %[whh] offset:16\n\t"
        "global_load_dwordx4 v[136:139], %[off3], %[whh] offset:32\n\t"
        "global_load_dwordx4 v[140:143], %[off3], %[whh] offset:48\n\t"
        "v_add_u32 v181, s31, %[off3]\n\t"
        "global_load_dwordx4 v[144:147], v181, %[whh] offset:0\n\t"
        "global_load_dwordx4 v[148:151], v181, %[whh] offset:16\n\t"
        "global_load_dwordx4 v[152:155], v181, %[whh] offset:32\n\t"
        "global_load_dwordx4 v[156:159], v181, %[whh] offset:48\n\t"
        // W_lin (own chunk then other chunk) -> v[188:219]
        "global_load_dwordx4 v[188:191], %[offL], %[wlin] offset:0\n\t"
        "global_load_dwordx4 v[192:195], %[offL], %[wlin] offset:16\n\t"
        "global_load_dwordx4 v[196:199], %[offL], %[wlin] offset:32\n\t"
        "global_load_dwordx4 v[200:203], %[offL], %[wlin] offset:48\n\t"
        "v_add_u32 v181, s31, %[offL]\n\t"
        "global_load_dwordx4 v[204:207], v181, %[wlin] offset:0\n\t"
        "global_load_dwordx4 v[208:211], v181, %[wlin] offset:16\n\t"
        "global_load_dwordx4 v[212:215], v181, %[wlin] offset:32\n\t"
        "global_load_dwordx4 v[216:219], v181, %[wlin] offset:48\n\t"
        "s_waitcnt vmcnt(0)\n\t"
        // fold: W' = W + wih*W_lin (chunk order matches), then exp2 pre-scale
        ".set K_I, 0\n"
        ".rept 32\n"
        " v_fma_f32 v[32+K_I],  %[wA], v[188+K_I], v[32+K_I]\n"
        " v_fma_f32 v[64+K_I],  %[wB], v[188+K_I], v[64+K_I]\n"
        " v_fma_f32 v[96+K_I],  %[wC], v[188+K_I], v[96+K_I]\n"
        " v_fma_f32 v[128+K_I], %[wD], v[188+K_I], v[128+K_I]\n"
        " .set K_I, K_I+1\n"
        ".endr\n"
        ".set K_I, 0\n"
        ".rept 32\n"
        " v_mul_f32 v[32+K_I],  %[sc0], v[32+K_I]\n"
        " v_mul_f32 v[64+K_I],  %[sc1], v[64+K_I]\n"
        " v_mul_f32 v[96+K_I],  %[sc2], v[96+K_I]\n"
        " v_mul_f32 v[128+K_I], %[sc3], v[128+K_I]\n"
        " .set K_I, K_I+1\n"
        ".endr\n"
        "s_movk_i32 s24, 1\n\t"
        "s_mov_b32 s25, 0\n\t"
        // initial skew seed: beta crew delays ~450cy
        "s_cmp_eq_u32 s29, 1\n\t"
        "s_cbranch_scc0 4f\n\t"
        ".rept 56\n s_nop 7\n .endr\n"
        "4:\n\t"
        // ---------------- main loop: t = 1 .. 2047 ----------------
        "1:\n\t"
        // ---- sibling check: own-crew flags >= t-1 guard own-chunk data ----
        "ds_read_b32 v180, v177\n\t"
        "s_waitcnt lgkmcnt(0)\n\t"
        "v_cmp_gt_u32 vcc, s25, v180\n\t"
        "s_cbranch_vccz 6f\n\t"
        "s_mov_b32 s21, 0\n\t"
        "5:\n\t"
        "s_sleep 1\n\t"
        "ds_read_b32 v180, v177\n\t"
        "s_waitcnt lgkmcnt(0)\n\t"
        "s_addk_i32 s21, 1\n\t"
        "s_cmpk_gt_u32 s21, 0x4000\n\t"
        "s_cbranch_scc1 6f\n\t"
        "v_cmp_gt_u32 vcc, s25, v180\n\t"
        "s_cbranch_vccnz 5b\n\t"
        "6:\n\t"
        // ---- own-chunk reads + foreign flag read (in-order DS) ----
        "ds_read_b128 v[0:3],   v172\n\t"
        "ds_read_b128 v[4:7],   v172 offset:16\n\t"
        "ds_read_b128 v[8:11],  v172 offset:32\n\t"
        "ds_read_b128 v[12:15], v172 offset:48\n\t"
        "ds_read_b32 v180, v178\n\t"
        // ---- own-chunk GEMV: 8 pairs x 4 slots, staggered ----
        "s_waitcnt lgkmcnt(4)\n\t"
        "v_pk_fma_f32 v[160:161], v[0:1], v[32:33], v[220:221]\n\t"
        "v_pk_fma_f32 v[162:163], v[0:1], v[64:65], v[222:223]\n\t"
        "v_pk_fma_f32 v[164:165], v[0:1], v[96:97], v[224:225]\n\t"
        "v_pk_fma_f32 v[166:167], v[0:1], v[128:129], v[226:227]\n\t"
        ".set K_I, 2\n"
        ".rept 1\n"
        " v_pk_fma_f32 v[160:161], v[K_I:K_I+1], v[32+K_I:33+K_I], v[160:161]\n"
        " v_pk_fma_f32 v[162:163], v[K_I:K_I+1], v[64+K_I:65+K_I], v[162:163]\n"
        " v_pk_fma_f32 v[164:165], v[K_I:K_I+1], v[96+K_I:97+K_I], v[164:165]\n"
        " v_pk_fma_f32 v[166:167], v[K_I:K_I+1], v[128+K_I:129+K_I], v[166:167]\n"
        " .set K_I, K_I+2\n"
        ".endr\n"
        "s_waitcnt lgkmcnt(3)\n\t"
        ".rept 2\n"
        " v_pk_fma_f32 v[160:161], v[K_I:K_I+1], v[32+K_I:33+K_I], v[160:161]\n"
        " v_pk_fma_f32 v[162:163], v[K_I:K_I+1], v[64+K_I:65+K_I], v[162:163]\n"
        " v_pk_fma_f32 v[164:165], v[K_I:K_I+1], v[96+K_I:97+K_I], v[164:165]\n"
        " v_pk_fma_f32 v[166:167], v[K_I:K_I+1], v[128+K_I:129+K_I], v[166:167]\n"
        " .set K_I, K_I+2\n"
        ".endr\n"
        "s_waitcnt lgkmcnt(2)\n\t"
        ".rept 2\n"
        " v_pk_fma_f32 v[160:161], v[K_I:K_I+1], v[32+K_I:33+K_I], v[160:161]\n"
        " v_pk_fma_f32 v[162:163], v[K_I:K_I+1], v[64+K_I:65+K_I], v[162:163]\n"
        " v_pk_fma_f32 v[164:165], v[K_I:K_I+1], v[96+K_I:97+K_I], v[164:165]\n"
        " v_pk_fma_f32 v[166:167], v[K_I:K_I+1], v[128+K_I:129+K_I], v[166:167]\n"
        " .set K_I, K_I+2\n"
        ".endr\n"
        "s_waitcnt lgkmcnt(1)\n\t"
        ".rept 2\n"
        " v_pk_fma_f32 v[160:161], v[K_I:K_I+1], v[32+K_I:33+K_I], v[160:161]\n"
        " v_pk_fma_f32 v[162:163], v[K_I:K_I+1], v[64+K_I:65+K_I], v[162:163]\n"
        " v_pk_fma_f32 v[164:165], v[K_I:K_I+1], v[96+K_I:97+K_I], v[164:165]\n"
        " v_pk_fma_f32 v[166:167], v[K_I:K_I+1], v[128+K_I:129+K_I], v[166:167]\n"
        " .set K_I, K_I+2\n"
        ".endr\n"
        // ---- foreign check (flag value arrived behind own-chunk reads) ----
        "s_waitcnt lgkmcnt(0)\n\t"
        "v_cmp_gt_u32 vcc, s25, v180\n\t"
        "s_cbranch_vccz 8f\n\t"
        "s_mov_b32 s21, 0\n\t"
        "7:\n\t"
        "s_sleep 1\n\t"
        "ds_read_b32 v180, v178\n\t"
        "s_waitcnt lgkmcnt(0)\n\t"
        "s_addk_i32 s21, 1\n\t"
        "s_cmpk_gt_u32 s21, 0x4000\n\t"
        "s_cbranch_scc1 8f\n\t"
        "v_cmp_gt_u32 vcc, s25, v180\n\t"
        "s_cbranch_vccnz 7b\n\t"
        "8:\n\t"
        // ---- other-chunk reads ----
        "v_add_u32 v183, s30, v172\n\t"
        "ds_read_b128 v[16:19], v183\n\t"
        "ds_read_b128 v[20:23], v183 offset:16\n\t"
        "ds_read_b128 v[24:27], v183 offset:32\n\t"
        "ds_read_b128 v[28:31], v183 offset:48\n\t"
        // ---- other-chunk GEMV: 8 pairs x 4 slots, staggered ----
        "s_waitcnt lgkmcnt(3)\n\t"
        ".set K_I, 16\n"
        ".rept 2\n"
        " v_pk_fma_f32 v[160:161], v[K_I:K_I+1], v[32+K_I:33+K_I], v[160:161]\n"
        " v_pk_fma_f32 v[162:163], v[K_I:K_I+1], v[64+K_I:65+K_I], v[162:163]\n"
        " v_pk_fma_f32 v[164:165], v[K_I:K_I+1], v[96+K_I:97+K_I], v[164:165]\n"
        " v_pk_fma_f32 v[166:167], v[K_I:K_I+1], v[128+K_I:129+K_I], v[166:167]\n"
        " .set K_I, K_I+2\n"
        ".endr\n"
        "s_waitcnt lgkmcnt(2)\n\t"
        ".rept 2\n"
        " v_pk_fma_f32 v[160:161], v[K_I:K_I+1], v[32+K_I:33+K_I], v[160:161]\n"
        " v_pk_fma_f32 v[162:163], v[K_I:K_I+1], v[64+K_I:65+K_I], v[162:163]\n"
        " v_pk_fma_f32 v[164:165], v[K_I:K_I+1], v[96+K_I:97+K_I], v[164:165]\n"
        " v_pk_fma_f32 v[166:167], v[K_I:K_I+1], v[128+K_I:129+K_I], v[166:167]\n"
        " .set K_I, K_I+2\n"
        ".endr\n"
        "s_waitcnt lgkmcnt(1)\n\t"
        ".rept 2\n"
        " v_pk_fma_f32 v[160:161], v[K_I:K_I+1], v[32+K_I:33+K_I], v[160:161]\n"
        " v_pk_fma_f32 v[162:163], v[K_I:K_I+1], v[64+K_I:65+K_I], v[162:163]\n"
        " v_pk_fma_f32 v[164:165], v[K_I:K_I+1], v[96+K_I:97+K_I], v[164:165]\n"
        " v_pk_fma_f32 v[166:167], v[K_I:K_I+1], v[128+K_I:129+K_I], v[166:167]\n"
        " .set K_I, K_I+2\n"
        ".endr\n"
        "s_waitcnt lgkmcnt(0)\n\t"
        ".rept 2\n"
        " v_pk_fma_f32 v[160:161], v[K_I:K_I+1], v[32+K_I:33+K_I], v[160:161]\n"
        " v_pk_fma_f32 v[162:163], v[K_I:K_I+1], v[64+K_I:65+K_I], v[162:163]\n"
        " v_pk_fma_f32 v[164:165], v[K_I:K_I+1], v[96+K_I:97+K_I], v[164:165]\n"
        " v_pk_fma_f32 v[166:167], v[K_I:K_I+1], v[128+K_I:129+K_I], v[166:167]\n"
        " .set K_I, K_I+2\n"
        ".endr\n"
        // ---- collapse lo+hi: slot sums (slot p = gate p^q) ----
        "v_add_f32 v160, v160, v161\n\t"
        "v_add_f32 v161, v162, v163\n\t"
        "v_add_f32 v164, v164, v165\n\t"
        "v_add_f32 v165, v166, v167\n\t"
        // ---- 3-DPP gate butterfly: v160 <- FULL sum of gate q on lane q ----
        "s_nop 1\n\t"
        "v_add_f32_dpp v160, v161, v160 quad_perm:[1,0,3,2] row_mask:0xf bank_mask:0xf\n\t"
        "v_add_f32_dpp v164, v165, v164 quad_perm:[1,0,3,2] row_mask:0xf bank_mask:0xf\n\t"
        // ptr advance fills the DPP gap: v174 -> write(t), v172 -> read(t+1)
        "v_add_u32 v174, 0x240, v174\n\t"
        "v_add_u32 v172, v174, v186\n\t"
        "s_nop 1\n\t"
        "v_add_f32_dpp v160, v164, v160 quad_perm:[2,3,0,1] row_mask:0xf bank_mask:0xf\n\t"
        // ---- single activation path (values pre-scaled for exp2) ----
        "s_nop 3\n\t"
        "v_exp_f32 v160, v160\n\t"
        "s_nop 1\n\t"
        "v_add_f32 v160, 1.0, v160\n\t"
        "v_rcp_f32 v160, v160\n\t"
        "s_nop 1\n\t"
        "v_fma_f32 v166, %[ca], v160, %[cb]\n\t"   // a = sigmoid / tanh of gate q
        // ---- quad redistribute: ig, f, o ----
        "s_nop 3\n\t"
        "v_mul_f32_dpp v161, v166, v166 quad_perm:[2,3,0,1] row_mask:0xf bank_mask:0xf\n\t"
        "v_mov_b32_dpp v162, v166 quad_perm:[1,0,3,2] row_mask:0xf bank_mask:0xf\n\t"
        "v_mov_b32_dpp v165, v166 quad_perm:[3,3,3,3] row_mask:0xf bank_mask:0xf\n\t"
        "s_nop 2\n\t"
        "v_fma_f32 v168, v162, v168, v161\n\t"     // c = f*c + i*g  (lane0 exact)
        // tanh(c)
        "v_mul_f32 v163, 0x4038aa3b, v168\n\t"
        "v_exp_f32 v163, v163\n\t"
        "s_nop 1\n\t"
        "v_add_f32 v163, 1.0, v163\n\t"
        "v_rcp_f32 v163, v163\n\t"
        "s_nop 1\n\t"
        "v_fma_f32 v163, -2.0, v163, 1.0\n\t"
        "v_mul_f32 v169, v165, v163\n\t"           // hn = o * tanh(c)
        // ---- publish: h (q==0 lanes) then flags[w]=t (lane 0) ----
        "v_mov_b32 v180, s24\n\t"
        "s_mov_b64 s[22:23], exec\n\t"
        "s_mov_b64 exec, s[26:27]\n\t"
        "ds_write_b32 v174, v169\n\t"
        "s_mov_b64 exec, 1\n\t"
        "ds_write_b32 v179, v180\n\t"
        "s_mov_b64 exec, s[22:23]\n\t"
        // ---- flush every 128 steps (full barrier; crews resync) ----
        "s_and_b32 s20, s24, 127\n\t"
        "s_cmp_lg_u32 s20, 127\n\t"
        "s_cbranch_scc1 3f\n\t"
        "s_waitcnt lgkmcnt(0)\n\t"
        "s_barrier\n\t"
        "v_add_u32 v174, 0xfffee000, v174\n\t"   // write base wrap: -73728
        // FLUSH FIX: own-chunk + other-chunk reads (match v[188:219] order)
        "ds_read_b128 v[0:3],   v184\n\t"
        "ds_read_b128 v[4:7],   v184 offset:16\n\t"
        "ds_read_b128 v[8:11],  v184 offset:32\n\t"
        "ds_read_b128 v[12:15], v184 offset:48\n\t"
        "v_add_u32 v183, s30, v184\n\t"
        "ds_read_b128 v[16:19], v183\n\t"
        "ds_read_b128 v[20:23], v183 offset:16\n\t"
        "ds_read_b128 v[24:27], v183 offset:32\n\t"
        "ds_read_b128 v[28:31], v183 offset:48\n\t"
        "v_mov_b32 v164, 0\n\t"
        "s_waitcnt lgkmcnt(0)\n\t"
        ".set K_I, 0\n"
        ".rept 32\n"
        " v_fma_f32 v164, v[0+K_I], v[188+K_I], v164\n"
        " .set K_I, K_I+1\n"
        ".endr\n"
        "s_nop 1\n\t"
        "v_add_f32_dpp v164, v164, v164 quad_perm:[1,0,3,2] row_mask:0xf bank_mask:0xf\n\t"
        "s_nop 1\n\t"
        "v_add_f32_dpp v164, v164, v164 quad_perm:[2,3,0,1] row_mask:0xf bank_mask:0xf\n\t"
        "v_add_f32 v164, v164, v185\n\t"         // + b_lin
        "v_add_u32 v170, s28, v171\n\t"          // out byte = base + j*1024
        "s_mov_b64 s[22:23], exec\n\t"
        "s_mov_b64 exec, s[26:27]\n\t"
        "global_store_dword v170, v164, %[outp]\n\t"
        "s_mov_b64 exec, s[22:23]\n\t"
        "s_add_u32 s28, s28, 0x20000\n\t"        // out base += 128*256*4
        "s_barrier\n\t"                           // protect hist vs next iter
        // re-seed the crew skew (beta delays ~450cy)
        "s_cmp_eq_u32 s29, 1\n\t"
        "s_cbranch_scc0 3f\n\t"
        ".rept 56\n s_nop 7\n .endr\n"
        "3:\n\t"
        "s_mov_b32 s25, s24\n\t"
        "s_add_i32 s24, s24, 1\n\t"
        "s_cmp_lt_i32 s24, 2048\n\t"
        "s_cbranch_scc1 1b\n\t"
        :
        : [off0]"v"(off0), [off1]"v"(off1), [off2]"v"(off2), [off3]"v"(off3),
          [offL]"v"(offL), [whh]"s"(W_hh), [wlin]"s"(W_lin), [outp]"s"(out),
          [wA]"v"(wihA), [wB]"v"(wihB), [wC]"v"(wihC), [wD]"v"(wihD),
          [b0]"v"(b0s), [b1]"v"(b1s), [b2]"v"(b2s), [b3]"v"(b3s),
          [sc0]"v"(sc0), [sc1]"v"(sc1), [sc2]"v"(sc2), [sc3]"v"(sc3),
          [ca]"v"(caq), [cb]"v"(cbq),
          [blin]"s"(blin), [c0]"v"(c),
          [vR]"v"(vR0), [hW]"v"(hW0), [vD]"v"(vD0), [fR]"v"(fR0),
          [jO]"v"(jO0), [vO]"s"(vO0),
          [sibF]"v"(sibF0), [pubF]"v"(pubF0), [crewv]"v"(crewv)
        : "memory", "scc", "vcc",
          "s20","s21","s22","s23","s24","s25","s26","s27","s28","s29","s30","s31",
          "v0","v1","v2","v3","v4","v5","v6","v7","v8","v9",
          "v10","v11","v12","v13","v14","v15","v16","v17","v18","v19",
          "v20","v21","v22","v23","v24","v25","v26","v27","v28","v29",
          "v30","v31","v32","v33","v34","v35","v36","v37","v38","v39",
          "v40","v41","v42","v43","v44","v45","v46","v47","v48","v49",
          "v50","v51","v52","v53","v54","v55","v56","v57","v58","v59",
          "v60","v61","v62","v63","v64","v65","v66","v67","v68","v69",
          "v70","v71","v72","v73","v74","v75","v76","v77","v78","v79",
          "v80","v81","v82","v83","v84","v85","v86","v87","v88","v89",
          "v90","v91","v92","v93","v94","v95","v96","v97","v98","v99",
          "v100","v101","v102","v103","v104","v105","v106","v107","v108","v109",
          "v110","v111","v112","v113","v114","v115","v116","v117","v118","v119",
          "v120","v121","v122","v123","v124","v125","v126","v127","v128","v129",
          "v130","v131","v132","v133","v134","v135","v136","v137","v138","v139",
          "v140","v141","v142","v143","v144","v145","v146","v147","v148","v149",
          "v150","v151","v152","v153","v154","v155","v156","v157","v158","v159",
          "v160","v161","v162","v163","v164","v165","v166","v167","v168","v169",
          "v170","v171","v172","v173","v174","v175","v176","v177","v178","v179",
          "v180","v181","v182","v183","v184","v185","v186","v187","v188","v189",
          "v190","v191","v192","v193","v194","v195","v196","v197","v198","v199",
          "v200","v201","v202","v203","v204","v205","v206","v207","v208","v209",
          "v210","v211","v212","v213","v214","v215","v216","v217","v218","v219",
          "v220","v221","v222","v223","v224","v225","v226","v227");
    // no C epilogue: flush k=15 covers out[1920..2047]
}

extern "C" void kernel_launch(void* const* d_in, const int* in_sizes, int n_in,
                              void* d_out, int out_size, void* d_ws, size_t ws_size,
                              hipStream_t stream) {
    // inputs: 0 input (unused), 1 label, 2 h0, 3 W_ih, 4 W_hh,
    //         5 b_ih, 6 b_hh, 7 W_lin, 8 b_lin
    const int*   label = (const int*)  d_in[1];
    const float* h0    = (const float*)d_in[2];
    const float* W_ih  = (const float*)d_in[3];
    const float* W_hh  = (const float*)d_in[4];
    const float* b_ih  = (const float*)d_in[5];
    const float* b_hh  = (const float*)d_in[6];
    const float* W_lin = (const float*)d_in[7];
    const float* b_lin = (const float*)d_in[8];
    float* out = (float*)d_out;

    lstm_seq_kernel<<<dim3(BATCH), dim3(512), 0, stream>>>(
        label, h0, W_ih, W_hh, b_ih, b_hh, W_lin, b_lin, out);
}